// Round 2
// baseline (1993.943 us; speedup 1.0000x reference)
//
#include <hip/hip_runtime.h>
#include <math.h>

// ---------------- problem constants (match reference) ----------------
#define NRES   20000
#define NSSE   2000
#define NDOM   40
#define FIN    1302
#define NHEAD  4
#define DDIM   128
#define HD     512      // NHEAD*DDIM
#define OUTD   256
#define SSEIN  132      // DDIM+3+1
#define BN_EPS 1e-5f

__device__ __forceinline__ float leaky(float v) { return v > 0.f ? v : 0.2f * v; }

// ---------------- generic tiled f32 GEMM: C = A(MxK) @ B(KxN) ----------------
__global__ __launch_bounds__(256) void sgemm64(const float* __restrict__ A,
                                               const float* __restrict__ B,
                                               float* __restrict__ C,
                                               int M, int N, int K) {
    __shared__ float As[16][68];
    __shared__ float Bs[16][68];
    int t = threadIdx.x;
    int tx = t & 15, ty = t >> 4;
    int row0 = blockIdx.y * 64, col0 = blockIdx.x * 64;
    float acc[4][4] = {};
    for (int k0 = 0; k0 < K; k0 += 16) {
#pragma unroll
        for (int i = 0; i < 4; ++i) {
            int idx = t * 4 + i;
            int r = idx >> 4, kk = idx & 15;
            int gr = row0 + r, gk = k0 + kk;
            As[kk][r] = (gr < M && gk < K) ? A[(long)gr * K + gk] : 0.f;
        }
#pragma unroll
        for (int i = 0; i < 4; ++i) {
            int idx = t * 4 + i;
            int kk = idx >> 6, c = idx & 63;
            int gk = k0 + kk, gc = col0 + c;
            Bs[kk][c] = (gk < K && gc < N) ? B[(long)gk * N + gc] : 0.f;
        }
        __syncthreads();
#pragma unroll
        for (int kk = 0; kk < 16; ++kk) {
            float a[4], b[4];
#pragma unroll
            for (int i = 0; i < 4; ++i) a[i] = As[kk][ty * 4 + i];
#pragma unroll
            for (int j = 0; j < 4; ++j) b[j] = Bs[kk][tx * 4 + j];
#pragma unroll
            for (int i = 0; i < 4; ++i)
#pragma unroll
                for (int j = 0; j < 4; ++j) acc[i][j] += a[i] * b[j];
        }
        __syncthreads();
    }
#pragma unroll
    for (int i = 0; i < 4; ++i) {
        int r = row0 + ty * 4 + i;
        if (r >= M) continue;
#pragma unroll
        for (int j = 0; j < 4; ++j) {
            int c = col0 + tx * 4 + j;
            if (c < N) C[(long)r * N + c] = acc[i][j];
        }
    }
}

// ---------------- CSR build ----------------
__global__ void count_deg(const int* __restrict__ dst, int E, int* __restrict__ deg) {
    int i = blockIdx.x * blockDim.x + threadIdx.x;
    if (i < E) atomicAdd(&deg[dst[i]], 1);
}

__global__ __launch_bounds__(256) void exclusive_scan(const int* __restrict__ deg,
                                                      int* __restrict__ row_ptr, int N) {
    __shared__ int part[256];
    __shared__ int base[257];
    int t = threadIdx.x;
    int chunk = (N + 255) / 256;
    int lo = t * chunk, hi = min(lo + chunk, N);
    if (lo > N) lo = N;
    if (hi > N) hi = N;
    int s = 0;
    for (int i = lo; i < hi; ++i) s += deg[i];
    part[t] = s;
    __syncthreads();
    if (t == 0) {
        int r = 0;
        for (int i = 0; i < 256; ++i) { base[i] = r; r += part[i]; }
        base[256] = r;
    }
    __syncthreads();
    int run = base[t];
    for (int i = lo; i < hi; ++i) { row_ptr[i] = run; run += deg[i]; }
    if (t == 0) row_ptr[N] = base[256];
}

__global__ void csr_fill(const int* __restrict__ src, const int* __restrict__ dst, int E,
                         const int* __restrict__ row_ptr, int* __restrict__ cursor,
                         int* __restrict__ col) {
    int i = blockIdx.x * blockDim.x + threadIdx.x;
    if (i < E) {
        int d = dst[i];
        int p = row_ptr[d] + atomicAdd(&cursor[d], 1);
        col[p] = src[i];
    }
}

// ---------------- attention scores: es/ed per (node, head) ----------------
__global__ __launch_bounds__(256) void att_scores(const float* __restrict__ h,
                                                  const float* __restrict__ asrc,
                                                  const float* __restrict__ adst,
                                                  float* __restrict__ es,
                                                  float* __restrict__ ed, int N) {
    int wid = threadIdx.x >> 6, lane = threadIdx.x & 63;
    int n = blockIdx.x * 4 + wid;
    if (n >= N) return;
    const float* hr = h + (long)n * HD;
    float ps[NHEAD], pd[NHEAD];
#pragma unroll
    for (int hh = 0; hh < NHEAD; ++hh) {
        float s = 0.f, d = 0.f;
#pragma unroll
        for (int j = 0; j < 2; ++j) {
            int c = hh * DDIM + lane + j * 64;
            float v = hr[c];
            s += v * asrc[c];
            d += v * adst[c];
        }
        ps[hh] = s; pd[hh] = d;
    }
#pragma unroll
    for (int off = 32; off > 0; off >>= 1) {
#pragma unroll
        for (int hh = 0; hh < NHEAD; ++hh) {
            ps[hh] += __shfl_xor(ps[hh], off);
            pd[hh] += __shfl_xor(pd[hh], off);
        }
    }
    if (lane == 0) {
#pragma unroll
        for (int hh = 0; hh < NHEAD; ++hh) {
            es[n * NHEAD + hh] = ps[hh];
            ed[n * NHEAD + hh] = pd[hh];
        }
    }
}

// ---------------- GAT aggregation (block per dst node; softmax incl. self loop) --------
__global__ __launch_bounds__(256) void gat_aggregate(const float* __restrict__ h,
                                                     const float* __restrict__ es,
                                                     const float* __restrict__ ed,
                                                     const int* __restrict__ row_ptr,
                                                     const int* __restrict__ col,
                                                     const float* __restrict__ bias,
                                                     float* __restrict__ out,
                                                     int N, int concat) {
    int n = blockIdx.x;
    int t = threadIdx.x;
    int lane = t & 63, wid = t >> 6;
    int s0 = row_ptr[n], s1 = row_ptr[n + 1];

    float edv[NHEAD], vself[NHEAD];
#pragma unroll
    for (int hh = 0; hh < NHEAD; ++hh) {
        edv[hh] = ed[n * NHEAD + hh];
        vself[hh] = leaky(es[n * NHEAD + hh] + edv[hh]);
    }
    __shared__ float sred[4][NHEAD];
    __shared__ float m[NHEAD], den[NHEAD];

    // pass 1a: max per head
    float lm[NHEAD] = {-1e30f, -1e30f, -1e30f, -1e30f};
    for (int k = s0 + t; k < s1; k += 256) {
        int sn = col[k];
#pragma unroll
        for (int hh = 0; hh < NHEAD; ++hh)
            lm[hh] = fmaxf(lm[hh], leaky(es[sn * NHEAD + hh] + edv[hh]));
    }
#pragma unroll
    for (int off = 32; off > 0; off >>= 1)
#pragma unroll
        for (int hh = 0; hh < NHEAD; ++hh) lm[hh] = fmaxf(lm[hh], __shfl_xor(lm[hh], off));
    if (lane == 0)
#pragma unroll
        for (int hh = 0; hh < NHEAD; ++hh) sred[wid][hh] = lm[hh];
    __syncthreads();
    if (t < NHEAD) {
        float mm = vself[t];
#pragma unroll
        for (int w = 0; w < 4; ++w) mm = fmaxf(mm, sred[w][t]);
        m[t] = mm;
    }
    __syncthreads();
    float mh[NHEAD];
#pragma unroll
    for (int hh = 0; hh < NHEAD; ++hh) mh[hh] = m[hh];

    // pass 1b: denominator
    float ls[NHEAD] = {0.f, 0.f, 0.f, 0.f};
    for (int k = s0 + t; k < s1; k += 256) {
        int sn = col[k];
#pragma unroll
        for (int hh = 0; hh < NHEAD; ++hh)
            ls[hh] += expf(leaky(es[sn * NHEAD + hh] + edv[hh]) - mh[hh]);
    }
#pragma unroll
    for (int off = 32; off > 0; off >>= 1)
#pragma unroll
        for (int hh = 0; hh < NHEAD; ++hh) ls[hh] += __shfl_xor(ls[hh], off);
    if (lane == 0)
#pragma unroll
        for (int hh = 0; hh < NHEAD; ++hh) sred[wid][hh] = ls[hh];
    __syncthreads();
    if (t < NHEAD)
        den[t] = sred[0][t] + sred[1][t] + sred[2][t] + sred[3][t] + expf(vself[t] - m[t]);
    __syncthreads();
    float inv[NHEAD];
#pragma unroll
    for (int hh = 0; hh < NHEAD; ++hh) inv[hh] = 1.f / (den[hh] + 1e-16f);

    // pass 2: weighted accumulate; LDS-staged alpha per 64-edge chunk
    int d0 = t, d1 = t + 256;
    int h0 = t >> 7, h1 = h0 + 2;
    float acc0, acc1;
    {
        float a0 = expf(vself[h0] - mh[h0]) * inv[h0];
        float a1 = expf(vself[h1] - mh[h1]) * inv[h1];
        acc0 = a0 * h[(long)n * HD + d0];
        acc1 = a1 * h[(long)n * HD + d1];
    }
    __shared__ float alph[64 * NHEAD];
    for (int base = s0; base < s1; base += 64) {
        int cnt = min(64, s1 - base);
        if (t < cnt * NHEAD) {
            int e = t >> 2, hh = t & 3;
            int sn = col[base + e];
            float v = leaky(es[sn * NHEAD + hh] + edv[hh]);
            alph[(e << 2) | hh] = expf(v - mh[hh]) * inv[hh];
        }
        __syncthreads();
        for (int e = 0; e < cnt; ++e) {
            int sn = col[base + e];
            const float* hs = h + (long)sn * HD;
            acc0 += alph[(e << 2) | h0] * hs[d0];
            acc1 += alph[(e << 2) | h1] * hs[d1];
        }
        __syncthreads();
    }

    if (concat) {
        out[(long)n * HD + d0] = acc0 + bias[d0];
        out[(long)n * HD + d1] = acc1 + bias[d1];
    } else {
        __shared__ float accs[HD];
        accs[d0] = acc0;
        accs[d1] = acc1;
        __syncthreads();
        if (t < DDIM)
            out[(long)n * DDIM + t] =
                (accs[t] + accs[t + 128] + accs[t + 256] + accs[t + 384]) * 0.25f + bias[t];
    }
}

// ---------------- BatchNorm (training-mode batch stats) + ReLU ----------------
__global__ __launch_bounds__(256) void bn_stats(const float* __restrict__ x,
                                                float* __restrict__ sums, long total, int C) {
    long gid = (long)blockIdx.x * blockDim.x + threadIdx.x;
    long stride = (long)gridDim.x * blockDim.x;  // must be a multiple of C
    int c = (int)(gid % C);
    float s = 0.f, s2 = 0.f;
    for (long i = gid; i < total; i += stride) {
        float v = x[i];
        s += v; s2 += v * v;
    }
    atomicAdd(&sums[c], s);
    atomicAdd(&sums[C + c], s2);
}

__global__ void bn_finalize(const float* __restrict__ sums, const float* __restrict__ g,
                            const float* __restrict__ be, float* __restrict__ ab,
                            float invN, int C) {
    int c = blockIdx.x * blockDim.x + threadIdx.x;
    if (c < C) {
        float mean = sums[c] * invN;
        float var = sums[C + c] * invN - mean * mean;
        float sc = g[c] * rsqrtf(var + BN_EPS);
        ab[c] = sc;
        ab[C + c] = be[c] - mean * sc;
    }
}

__global__ __launch_bounds__(256) void bn_apply_relu(const float* __restrict__ x,
                                                     const float* __restrict__ ab,
                                                     float* __restrict__ y, long total, int C) {
    long gid = (long)blockIdx.x * blockDim.x + threadIdx.x;
    long stride = (long)gridDim.x * blockDim.x;
    for (long i = gid; i < total; i += stride) {
        int c = (int)(i % C);
        y[i] = fmaxf(0.f, x[i] * ab[c] + ab[C + c]);
    }
}

// ---------------- residue -> SSE pooling ----------------
__global__ void count_res(const int* __restrict__ sid, float* __restrict__ cnt, int Nr) {
    int i = blockIdx.x * blockDim.x + threadIdx.x;
    if (i < Nr) atomicAdd(&cnt[sid[i]], 1.f);
}

__global__ __launch_bounds__(256) void pool_res(const float* __restrict__ x,
                                                const int* __restrict__ sid,
                                                float* __restrict__ pooled, int Nr) {
    long total = (long)Nr * DDIM;
    long stride = (long)gridDim.x * blockDim.x;
    for (long i = (long)blockIdx.x * blockDim.x + threadIdx.x; i < total; i += stride) {
        int n = (int)(i / DDIM), c = (int)(i % DDIM);
        atomicAdd(&pooled[(long)sid[n] * DDIM + c], x[i]);
    }
}

__global__ void build_xsse(const float* __restrict__ pooled, const float* __restrict__ cnt,
                           const int* __restrict__ sstype, float* __restrict__ xsse, int Ns) {
    int i = blockIdx.x * blockDim.x + threadIdx.x;
    if (i >= Ns * SSEIN) return;
    int s = i / SSEIN, j = i % SSEIN;
    float c = cnt[s];
    float v;
    if (j < DDIM) v = pooled[(long)s * DDIM + j] / fmaxf(c, 1.f);
    else if (j < DDIM + 3) v = (sstype[s] == (j - DDIM)) ? 1.f : 0.f;
    else v = c / (float)NRES;
    xsse[i] = v;
}

// ---------------- SSE -> domain pooling (contiguous partition, remainder to last) -----
__global__ void pool_dom(const float* __restrict__ x, float* __restrict__ xdom) {
    int d = blockIdx.x, c = threadIdx.x;  // 40 blocks x 128 threads
    int spd = NSSE / NDOM;
    int r0 = d * spd;
    int r1 = (d == NDOM - 1) ? NSSE : r0 + spd;
    float acc = 0.f;
    for (int r = r0; r < r1; ++r) acc += x[(long)r * DDIM + c];
    xdom[d * DDIM + c] = acc / (float)(r1 - r0);
}

// ---------------- domain GCN ----------------
__global__ __launch_bounds__(256) void gcn_prep(const int* __restrict__ src,
                                                const int* __restrict__ dst, int E,
                                                float* __restrict__ dis) {
    __shared__ float degL[NDOM];
    int t = threadIdx.x;
    if (t < NDOM) degL[t] = 1.f;  // self loop
    __syncthreads();
    for (int e = t; e < E; e += blockDim.x) atomicAdd(&degL[dst[e]], 1.f);
    __syncthreads();
    if (t < NDOM) dis[t] = rsqrtf(fmaxf(degL[t], 1e-12f));
}

__global__ void gcn_agg(const float* __restrict__ hdom, const int* __restrict__ src,
                        const int* __restrict__ dst, int E, const float* __restrict__ dis,
                        const float* __restrict__ bd, float* __restrict__ outd) {
    int n = blockIdx.x, c = threadIdx.x;  // 40 blocks x 256 threads
    float dn = dis[n];
    float acc = dn * dn * hdom[n * OUTD + c];
    for (int e = 0; e < E; ++e)
        if (dst[e] == n) acc += dis[src[e]] * dn * hdom[src[e] * OUTD + c];
    outd[n * OUTD + c] = acc + bd[c];
}

__global__ void bn_small_relu(const float* __restrict__ x, const float* __restrict__ g,
                              const float* __restrict__ be, float* __restrict__ y,
                              int N, int C) {
    int c = threadIdx.x;
    if (c >= C) return;
    float s = 0.f, s2 = 0.f;
    for (int r = 0; r < N; ++r) {
        float v = x[r * C + c];
        s += v; s2 += v * v;
    }
    float mean = s / N;
    float var = s2 / N - mean * mean;
    float sc = g[c] * rsqrtf(var + BN_EPS);
    float sh = be[c] - mean * sc;
    for (int r = 0; r < N; ++r) y[r * C + c] = fmaxf(0.f, x[r * C + c] * sc + sh);
}

// ---------------- readout ----------------
__global__ void col_mean(const float* __restrict__ x, float* __restrict__ out, int N, int C) {
    int c = threadIdx.x;
    if (c >= C) return;
    float s = 0.f;
    for (int r = 0; r < N; ++r) s += x[(long)r * C + c];
    out[c] = s / (float)N;
}

__global__ __launch_bounds__(256) void readout(const float* __restrict__ sse_global,
                                               const float* __restrict__ xdom_bn,
                                               const float* __restrict__ Wproj,
                                               const float* __restrict__ bproj,
                                               const float* __restrict__ Wread,
                                               const float* __restrict__ bread,
                                               float* __restrict__ out) {
    int c = threadIdx.x;  // 256
    __shared__ float v[2 * OUTD];
    float s = bproj[c];
    for (int k = 0; k < DDIM; ++k) s += sse_global[k] * Wproj[k * OUTD + c];
    v[c] = s;
    float dm = 0.f;
    for (int r = 0; r < NDOM; ++r) dm += xdom_bn[r * OUTD + c];
    v[OUTD + c] = dm / (float)NDOM;
    __syncthreads();
    float o = bread[c];
    for (int k = 0; k < 2 * OUTD; ++k) o += v[k] * Wread[k * OUTD + c];
    __shared__ float sq[256];
    sq[c] = o * o;
    __syncthreads();
    for (int off = 128; off > 0; off >>= 1) {
        if (c < off) sq[c] += sq[c + off];
        __syncthreads();
    }
    float scale = 1.f / fmaxf(sqrtf(sq[0]), 1e-12f);
    out[c] = o * scale;
}

// ---------------- launcher ----------------
extern "C" void kernel_launch(void* const* d_in, const int* in_sizes, int n_in,
                              void* d_out, int out_size, void* d_ws, size_t ws_size,
                              hipStream_t stream) {
    const float* x_res = (const float*)d_in[0];
    const int* ei_res = (const int*)d_in[1];
    const int* ei_sse = (const int*)d_in[2];
    const int* ei_dom = (const int*)d_in[3];
    const int* res_sse_id = (const int*)d_in[4];
    const int* sse_ss = (const int*)d_in[5];
    const int E_res = in_sizes[1] / 2;
    const int E_sse = in_sizes[2] / 2;
    const int E_dom = in_sizes[3] / 2;
    const int Nr = in_sizes[4];   // 20000
    const int Ns = in_sizes[5];   // 2000
    const float* W1 = (const float*)d_in[7];
    const float* asrc1 = (const float*)d_in[8];
    const float* adst1 = (const float*)d_in[9];
    const float* b1 = (const float*)d_in[10];
    const float* g1 = (const float*)d_in[11];
    const float* be1 = (const float*)d_in[12];
    const float* W2 = (const float*)d_in[13];
    const float* asrc2 = (const float*)d_in[14];
    const float* adst2 = (const float*)d_in[15];
    const float* b2 = (const float*)d_in[16];
    const float* g2 = (const float*)d_in[17];
    const float* be2 = (const float*)d_in[18];
    const float* Ws = (const float*)d_in[19];
    const float* asrcs = (const float*)d_in[20];
    const float* adsts = (const float*)d_in[21];
    const float* bs = (const float*)d_in[22];
    const float* gs = (const float*)d_in[23];
    const float* bes = (const float*)d_in[24];
    const float* Wd = (const float*)d_in[25];
    const float* bd = (const float*)d_in[26];
    const float* gd = (const float*)d_in[27];
    const float* bed = (const float*)d_in[28];
    const float* Wproj = (const float*)d_in[29];
    const float* bproj = (const float*)d_in[30];
    const float* Wread = (const float*)d_in[31];
    const float* bread = (const float*)d_in[32];

    // ---- workspace layout (defensive: clamp to ws_size; total ~102 MB) ----
    char* w = (char*)d_ws;
    size_t off = 0;
    auto alloc = [&](size_t bytes) -> char* {
        char* p = w + off;
        size_t inc = (bytes + 255) & ~(size_t)255;
        if (off + inc > ws_size) inc = (off < ws_size) ? (ws_size - off) : 0; // never exceed
        off += inc;
        return p;
    };
    float* A     = (float*)alloc((size_t)Nr * HD * 4);   // h1 / h2
    float* Bb    = (float*)alloc((size_t)Nr * HD * 4);   // gat1 out / bn1 (in place)
    float* C2    = (float*)alloc((size_t)Nr * DDIM * 4); // gat2 out / bn2 (in place)
    float* es    = (float*)alloc((size_t)Nr * NHEAD * 4);
    float* ed    = (float*)alloc((size_t)Nr * NHEAD * 4);
    int* rp_res  = (int*)alloc((size_t)(Nr + 1) * 4);
    int* col_res = (int*)alloc((size_t)E_res * 4);
    int* rp_sse  = (int*)alloc((size_t)(Ns + 1) * 4);
    int* col_sse = (int*)alloc((size_t)E_sse * 4);
    float* xsse  = (float*)alloc((size_t)Ns * SSEIN * 4);
    float* h_s   = (float*)alloc((size_t)Ns * HD * 4);
    float* xs_o  = (float*)alloc((size_t)Ns * DDIM * 4); // gat_s out / bn_s (in place)
    float* xdom  = (float*)alloc((size_t)NDOM * DDIM * 4);
    float* hdom  = (float*)alloc((size_t)NDOM * OUTD * 4);
    float* gdom  = (float*)alloc((size_t)NDOM * OUTD * 4);
    float* gdom2 = (float*)alloc((size_t)NDOM * OUTD * 4);
    float* dis   = (float*)alloc((size_t)NDOM * 4);
    float* sse_g = (float*)alloc((size_t)DDIM * 4);
    float* ab1   = (float*)alloc((size_t)2 * HD * 4);
    float* ab2   = (float*)alloc((size_t)2 * DDIM * 4);
    float* ab_s  = (float*)alloc((size_t)2 * DDIM * 4);
    // zeroed region (single memset)
    char* zbase = w + off;
    int* deg_res  = (int*)alloc((size_t)Nr * 4);
    int* cur_res  = (int*)alloc((size_t)Nr * 4);
    int* deg_sse  = (int*)alloc((size_t)Ns * 4);
    int* cur_sse  = (int*)alloc((size_t)Ns * 4);
    float* cnt    = (float*)alloc((size_t)Ns * 4);
    float* pooled = (float*)alloc((size_t)Ns * DDIM * 4);
    float* bsum1  = (float*)alloc((size_t)2 * HD * 4);
    float* bsum2  = (float*)alloc((size_t)2 * DDIM * 4);
    float* bsum_s = (float*)alloc((size_t)2 * DDIM * 4);
    size_t zbytes = (size_t)((w + off) - zbase);
    (void)n_in; (void)out_size;

    hipMemsetAsync(zbase, 0, zbytes, stream);

    const int* src_res = ei_res;
    const int* dst_res = ei_res + E_res;
    const int* src_sse = ei_sse;
    const int* dst_sse = ei_sse + E_sse;
    const int* src_dom = ei_dom;
    const int* dst_dom = ei_dom + E_dom;

    // CSR for residue graph (shared by GAT1 & GAT2) and SSE graph
    count_deg<<<(E_res + 255) / 256, 256, 0, stream>>>(dst_res, E_res, deg_res);
    exclusive_scan<<<1, 256, 0, stream>>>(deg_res, rp_res, Nr);
    csr_fill<<<(E_res + 255) / 256, 256, 0, stream>>>(src_res, dst_res, E_res, rp_res, cur_res, col_res);
    count_deg<<<(E_sse + 255) / 256, 256, 0, stream>>>(dst_sse, E_sse, deg_sse);
    exclusive_scan<<<1, 256, 0, stream>>>(deg_sse, rp_sse, Ns);
    csr_fill<<<(E_sse + 255) / 256, 256, 0, stream>>>(src_sse, dst_sse, E_sse, rp_sse, cur_sse, col_sse);

    // ---- Level 1, GAT1 (concat) ----
    sgemm64<<<dim3(HD / 64, (Nr + 63) / 64), 256, 0, stream>>>(x_res, W1, A, Nr, HD, FIN);
    att_scores<<<(Nr + 3) / 4, 256, 0, stream>>>(A, asrc1, adst1, es, ed, Nr);
    gat_aggregate<<<Nr, 256, 0, stream>>>(A, es, ed, rp_res, col_res, b1, Bb, Nr, 1);
    bn_stats<<<512, 256, 0, stream>>>(Bb, bsum1, (long)Nr * HD, HD);
    bn_finalize<<<2, 256, 0, stream>>>(bsum1, g1, be1, ab1, 1.f / Nr, HD);
    bn_apply_relu<<<2048, 256, 0, stream>>>(Bb, ab1, Bb, (long)Nr * HD, HD);

    // ---- Level 1, GAT2 (mean heads) ----
    sgemm64<<<dim3(HD / 64, (Nr + 63) / 64), 256, 0, stream>>>(Bb, W2, A, Nr, HD, HD);
    att_scores<<<(Nr + 3) / 4, 256, 0, stream>>>(A, asrc2, adst2, es, ed, Nr);
    gat_aggregate<<<Nr, 256, 0, stream>>>(A, es, ed, rp_res, col_res, b2, C2, Nr, 0);
    bn_stats<<<512, 256, 0, stream>>>(C2, bsum2, (long)Nr * DDIM, DDIM);
    bn_finalize<<<1, 128, 0, stream>>>(bsum2, g2, be2, ab2, 1.f / Nr, DDIM);
    bn_apply_relu<<<2048, 256, 0, stream>>>(C2, ab2, C2, (long)Nr * DDIM, DDIM);

    // ---- pool residues -> SSE, build features ----
    count_res<<<(Nr + 255) / 256, 256, 0, stream>>>(res_sse_id, cnt, Nr);
    pool_res<<<2048, 256, 0, stream>>>(C2, res_sse_id, pooled, Nr);
    build_xsse<<<(Ns * SSEIN + 255) / 256, 256, 0, stream>>>(pooled, cnt, sse_ss, xsse, Ns);

    // ---- Level 2: SSE GAT (mean heads) ----
    sgemm64<<<dim3(HD / 64, (Ns + 63) / 64), 256, 0, stream>>>(xsse, Ws, h_s, Ns, HD, SSEIN);
    att_scores<<<(Ns + 3) / 4, 256, 0, stream>>>(h_s, asrcs, adsts, es, ed, Ns);
    gat_aggregate<<<Ns, 256, 0, stream>>>(h_s, es, ed, rp_sse, col_sse, bs, xs_o, Ns, 0);
    bn_stats<<<512, 256, 0, stream>>>(xs_o, bsum_s, (long)Ns * DDIM, DDIM);
    bn_finalize<<<1, 128, 0, stream>>>(bsum_s, gs, bes, ab_s, 1.f / Ns, DDIM);
    bn_apply_relu<<<512, 256, 0, stream>>>(xs_o, ab_s, xs_o, (long)Ns * DDIM, DDIM);

    // ---- pool SSE -> domains; GCN; BN ----
    pool_dom<<<NDOM, DDIM, 0, stream>>>(xs_o, xdom);
    sgemm64<<<dim3(OUTD / 64, 1), 256, 0, stream>>>(xdom, Wd, hdom, NDOM, OUTD, DDIM);
    gcn_prep<<<1, 256, 0, stream>>>(src_dom, dst_dom, E_dom, dis);
    gcn_agg<<<NDOM, OUTD, 0, stream>>>(hdom, src_dom, dst_dom, E_dom, dis, bd, gdom);
    bn_small_relu<<<1, OUTD, 0, stream>>>(gdom, gd, bed, gdom2, NDOM, OUTD);

    // ---- readout ----
    col_mean<<<1, DDIM, 0, stream>>>(xs_o, sse_g, Ns, DDIM);
    readout<<<1, OUTD, 0, stream>>>(sse_g, gdom2, Wproj, bproj, Wread, bread, (float*)d_out);
}

// Round 3
// 1417.360 us; speedup vs baseline: 1.4068x; 1.4068x over previous
//
#include <hip/hip_runtime.h>
#include <math.h>

// ---------------- problem constants (match reference) ----------------
#define NRES   20000
#define NSSE   2000
#define NDOM   40
#define FIN    1302
#define NHEAD  4
#define DDIM   128
#define HD     512      // NHEAD*DDIM
#define OUTD   256
#define SSEIN  132      // DDIM+3+1
#define BN_EPS 1e-5f
#define KP1    1312     // FIN padded to multiple of 32

typedef _Float16 f16;
typedef __attribute__((ext_vector_type(8))) _Float16 f16x8;
typedef __attribute__((ext_vector_type(4))) float f32x4;

__device__ __forceinline__ float leaky(float v) { return v > 0.f ? v : 0.2f * v; }

// ---------------- f32 -> (hi,lo) f16 split, row layout [M][Kpad], zero-padded ----------
__global__ __launch_bounds__(256) void split_rows(const float* __restrict__ X,
                                                  f16* __restrict__ hi, f16* __restrict__ lo,
                                                  int M, int K, int Kpad) {
    long slots = (long)M * (Kpad >> 3);
    long stride = (long)gridDim.x * blockDim.x;
    for (long s = (long)blockIdx.x * blockDim.x + threadIdx.x; s < slots; s += stride) {
        int m = (int)(s / (Kpad >> 3));
        int kc = (int)(s % (Kpad >> 3)) << 3;
        f16x8 h, l;
#pragma unroll
        for (int j = 0; j < 8; ++j) {
            int k = kc + j;
            float v = (k < K) ? X[(long)m * K + k] : 0.f;
            f16 hh = (f16)v;
            h[j] = hh;
            l[j] = (f16)(v - (float)hh);
        }
        long o = ((long)m * Kpad + kc);
        *(f16x8*)&hi[o] = h;
        *(f16x8*)&lo[o] = l;
    }
}

// ---------------- W[K][N] f32 -> transposed split [N][Kpad] --------------------------
__global__ __launch_bounds__(256) void split_w_t(const float* __restrict__ W,
                                                 f16* __restrict__ hi, f16* __restrict__ lo,
                                                 int K, int N, int Kpad) {
    long total = (long)N * Kpad;
    long stride = (long)gridDim.x * blockDim.x;
    for (long i = (long)blockIdx.x * blockDim.x + threadIdx.x; i < total; i += stride) {
        int n = (int)(i / Kpad), k = (int)(i % Kpad);
        float v = (k < K) ? W[(long)k * N + n] : 0.f;
        f16 h = (f16)v;
        hi[i] = h;
        lo[i] = (f16)(v - (float)h);
    }
}

// ---------------- BN apply + ReLU fused with hi/lo split (for GEMM2 input) -----------
__global__ __launch_bounds__(256) void bn_apply_split(const float* __restrict__ x,
                                                      const float* __restrict__ ab,
                                                      f16* __restrict__ hi, f16* __restrict__ lo,
                                                      long total, int C) {
    long stride = (long)gridDim.x * blockDim.x;
    for (long i = (long)blockIdx.x * blockDim.x + threadIdx.x; i < total; i += stride) {
        int c = (int)(i % C);
        float v = fmaxf(0.f, x[i] * ab[c] + ab[C + c]);
        f16 h = (f16)v;
        hi[i] = h;
        lo[i] = (f16)(v - (float)h);
    }
}

// ---------------- MFMA GEMM: C[M][N] = A @ B via f16 hi/lo 3-pass --------------------
// A (hi/lo): [M][Kpad] f16 row-major.  Bt (hi/lo): [N][Kpad] f16 (i.e. B transposed).
// tile 128x64, BK=32, 256 threads = 4 waves (2x2), each wave 64x32 via 4x2 16x16 frags.
__global__ __launch_bounds__(256) void mfma_gemm(const f16* __restrict__ Ahi,
                                                 const f16* __restrict__ Alo,
                                                 const f16* __restrict__ Bthi,
                                                 const f16* __restrict__ Btlo,
                                                 float* __restrict__ C,
                                                 int M, int N, int Kpad) {
    __shared__ f16 As[2][128][40];  // [hi/lo][row][k]  pitch 40 (80B) -> 2-way bank alias only
    __shared__ f16 Bs[2][64][40];   // [hi/lo][col][k]
    int t = threadIdx.x;
    int w = t >> 6, l = t & 63;
    int wr = w >> 1, wc = w & 1;
    int row0 = blockIdx.y * 128, col0 = blockIdx.x * 64;

    f32x4 acc[4][2] = {};

    for (int k0 = 0; k0 < Kpad; k0 += 32) {
        // stage A: 512 slots of 8 f16; thread t handles slots t and t+256
#pragma unroll
        for (int r = 0; r < 2; ++r) {
            int s = t + (r << 8);
            int row = s >> 2, kc = (s & 3) << 3;
            int grow = row0 + row; if (grow >= M) grow = M - 1;  // safe read; result discarded
            long gi = (long)grow * Kpad + k0 + kc;
            *(f16x8*)&As[0][row][kc] = *(const f16x8*)&Ahi[gi];
            *(f16x8*)&As[1][row][kc] = *(const f16x8*)&Alo[gi];
        }
        // stage B: 256 slots
        {
            int col = t >> 2, kc = (t & 3) << 3;
            long gi = (long)(col0 + col) * Kpad + k0 + kc;
            *(f16x8*)&Bs[0][col][kc] = *(const f16x8*)&Bthi[gi];
            *(f16x8*)&Bs[1][col][kc] = *(const f16x8*)&Btlo[gi];
        }
        __syncthreads();

        int lr = l & 15, ks = (l >> 4) << 3;
        f16x8 ah[4], al[4], bh[2], bl[2];
#pragma unroll
        for (int fi = 0; fi < 4; ++fi) {
            int row = wr * 64 + fi * 16 + lr;
            ah[fi] = *(const f16x8*)&As[0][row][ks];
            al[fi] = *(const f16x8*)&As[1][row][ks];
        }
#pragma unroll
        for (int fj = 0; fj < 2; ++fj) {
            int col = wc * 32 + fj * 16 + lr;
            bh[fj] = *(const f16x8*)&Bs[0][col][ks];
            bl[fj] = *(const f16x8*)&Bs[1][col][ks];
        }
#pragma unroll
        for (int fi = 0; fi < 4; ++fi)
#pragma unroll
            for (int fj = 0; fj < 2; ++fj) {
                acc[fi][fj] = __builtin_amdgcn_mfma_f32_16x16x32_f16(ah[fi], bh[fj], acc[fi][fj], 0, 0, 0);
                acc[fi][fj] = __builtin_amdgcn_mfma_f32_16x16x32_f16(ah[fi], bl[fj], acc[fi][fj], 0, 0, 0);
                acc[fi][fj] = __builtin_amdgcn_mfma_f32_16x16x32_f16(al[fi], bh[fj], acc[fi][fj], 0, 0, 0);
            }
        __syncthreads();
    }
    // epilogue: C/D layout (m89-verified): col = lane&15, row = (lane>>4)*4 + reg
    int lr = l & 15, lq = l >> 4;
#pragma unroll
    for (int fi = 0; fi < 4; ++fi)
#pragma unroll
        for (int fj = 0; fj < 2; ++fj)
#pragma unroll
            for (int r = 0; r < 4; ++r) {
                int row = row0 + wr * 64 + fi * 16 + lq * 4 + r;
                int col = col0 + wc * 32 + fj * 16 + lr;
                if (row < M) C[(long)row * N + col] = acc[fi][fj][r];
            }
}

// ---------------- generic tiled f32 GEMM (small GEMMs + fallback) ----------------
__global__ __launch_bounds__(256) void sgemm64(const float* __restrict__ A,
                                               const float* __restrict__ B,
                                               float* __restrict__ C,
                                               int M, int N, int K) {
    __shared__ float As[16][68];
    __shared__ float Bs[16][68];
    int t = threadIdx.x;
    int tx = t & 15, ty = t >> 4;
    int row0 = blockIdx.y * 64, col0 = blockIdx.x * 64;
    float acc[4][4] = {};
    for (int k0 = 0; k0 < K; k0 += 16) {
#pragma unroll
        for (int i = 0; i < 4; ++i) {
            int idx = t * 4 + i;
            int r = idx >> 4, kk = idx & 15;
            int gr = row0 + r, gk = k0 + kk;
            As[kk][r] = (gr < M && gk < K) ? A[(long)gr * K + gk] : 0.f;
        }
#pragma unroll
        for (int i = 0; i < 4; ++i) {
            int idx = t * 4 + i;
            int kk = idx >> 6, c = idx & 63;
            int gk = k0 + kk, gc = col0 + c;
            Bs[kk][c] = (gk < K && gc < N) ? B[(long)gk * N + gc] : 0.f;
        }
        __syncthreads();
#pragma unroll
        for (int kk = 0; kk < 16; ++kk) {
            float a[4], b[4];
#pragma unroll
            for (int i = 0; i < 4; ++i) a[i] = As[kk][ty * 4 + i];
#pragma unroll
            for (int j = 0; j < 4; ++j) b[j] = Bs[kk][tx * 4 + j];
#pragma unroll
            for (int i = 0; i < 4; ++i)
#pragma unroll
                for (int j = 0; j < 4; ++j) acc[i][j] += a[i] * b[j];
        }
        __syncthreads();
    }
#pragma unroll
    for (int i = 0; i < 4; ++i) {
        int r = row0 + ty * 4 + i;
        if (r >= M) continue;
#pragma unroll
        for (int j = 0; j < 4; ++j) {
            int c = col0 + tx * 4 + j;
            if (c < N) C[(long)r * N + c] = acc[i][j];
        }
    }
}

// ---------------- CSR build ----------------
__global__ void count_deg(const int* __restrict__ dst, int E, int* __restrict__ deg) {
    int i = blockIdx.x * blockDim.x + threadIdx.x;
    if (i < E) atomicAdd(&deg[dst[i]], 1);
}

__global__ __launch_bounds__(256) void exclusive_scan(const int* __restrict__ deg,
                                                      int* __restrict__ row_ptr, int N) {
    __shared__ int part[256];
    __shared__ int base[257];
    int t = threadIdx.x;
    int chunk = (N + 255) / 256;
    int lo = t * chunk, hi = min(lo + chunk, N);
    if (lo > N) lo = N;
    if (hi > N) hi = N;
    int s = 0;
    for (int i = lo; i < hi; ++i) s += deg[i];
    part[t] = s;
    __syncthreads();
    if (t == 0) {
        int r = 0;
        for (int i = 0; i < 256; ++i) { base[i] = r; r += part[i]; }
        base[256] = r;
    }
    __syncthreads();
    int run = base[t];
    for (int i = lo; i < hi; ++i) { row_ptr[i] = run; run += deg[i]; }
    if (t == 0) row_ptr[N] = base[256];
}

__global__ void csr_fill(const int* __restrict__ src, const int* __restrict__ dst, int E,
                         const int* __restrict__ row_ptr, int* __restrict__ cursor,
                         int* __restrict__ col) {
    int i = blockIdx.x * blockDim.x + threadIdx.x;
    if (i < E) {
        int d = dst[i];
        int p = row_ptr[d] + atomicAdd(&cursor[d], 1);
        col[p] = src[i];
    }
}

// ---------------- attention scores ----------------
__global__ __launch_bounds__(256) void att_scores(const float* __restrict__ h,
                                                  const float* __restrict__ asrc,
                                                  const float* __restrict__ adst,
                                                  float* __restrict__ es,
                                                  float* __restrict__ ed, int N) {
    int wid = threadIdx.x >> 6, lane = threadIdx.x & 63;
    int n = blockIdx.x * 4 + wid;
    if (n >= N) return;
    const float* hr = h + (long)n * HD;
    float ps[NHEAD], pd[NHEAD];
#pragma unroll
    for (int hh = 0; hh < NHEAD; ++hh) {
        float s = 0.f, d = 0.f;
#pragma unroll
        for (int j = 0; j < 2; ++j) {
            int c = hh * DDIM + lane + j * 64;
            float v = hr[c];
            s += v * asrc[c];
            d += v * adst[c];
        }
        ps[hh] = s; pd[hh] = d;
    }
#pragma unroll
    for (int off = 32; off > 0; off >>= 1) {
#pragma unroll
        for (int hh = 0; hh < NHEAD; ++hh) {
            ps[hh] += __shfl_xor(ps[hh], off);
            pd[hh] += __shfl_xor(pd[hh], off);
        }
    }
    if (lane == 0) {
#pragma unroll
        for (int hh = 0; hh < NHEAD; ++hh) {
            es[n * NHEAD + hh] = ps[hh];
            ed[n * NHEAD + hh] = pd[hh];
        }
    }
}

// ---------------- GAT aggregation ----------------
__global__ __launch_bounds__(256) void gat_aggregate(const float* __restrict__ h,
                                                     const float* __restrict__ es,
                                                     const float* __restrict__ ed,
                                                     const int* __restrict__ row_ptr,
                                                     const int* __restrict__ col,
                                                     const float* __restrict__ bias,
                                                     float* __restrict__ out,
                                                     int N, int concat) {
    int n = blockIdx.x;
    int t = threadIdx.x;
    int lane = t & 63, wid = t >> 6;
    int s0 = row_ptr[n], s1 = row_ptr[n + 1];

    float edv[NHEAD], vself[NHEAD];
#pragma unroll
    for (int hh = 0; hh < NHEAD; ++hh) {
        edv[hh] = ed[n * NHEAD + hh];
        vself[hh] = leaky(es[n * NHEAD + hh] + edv[hh]);
    }
    __shared__ float sred[4][NHEAD];
    __shared__ float m[NHEAD], den[NHEAD];

    float lm[NHEAD] = {-1e30f, -1e30f, -1e30f, -1e30f};
    for (int k = s0 + t; k < s1; k += 256) {
        int sn = col[k];
#pragma unroll
        for (int hh = 0; hh < NHEAD; ++hh)
            lm[hh] = fmaxf(lm[hh], leaky(es[sn * NHEAD + hh] + edv[hh]));
    }
#pragma unroll
    for (int off = 32; off > 0; off >>= 1)
#pragma unroll
        for (int hh = 0; hh < NHEAD; ++hh) lm[hh] = fmaxf(lm[hh], __shfl_xor(lm[hh], off));
    if (lane == 0)
#pragma unroll
        for (int hh = 0; hh < NHEAD; ++hh) sred[wid][hh] = lm[hh];
    __syncthreads();
    if (t < NHEAD) {
        float mm = vself[t];
#pragma unroll
        for (int w = 0; w < 4; ++w) mm = fmaxf(mm, sred[w][t]);
        m[t] = mm;
    }
    __syncthreads();
    float mh[NHEAD];
#pragma unroll
    for (int hh = 0; hh < NHEAD; ++hh) mh[hh] = m[hh];

    float ls[NHEAD] = {0.f, 0.f, 0.f, 0.f};
    for (int k = s0 + t; k < s1; k += 256) {
        int sn = col[k];
#pragma unroll
        for (int hh = 0; hh < NHEAD; ++hh)
            ls[hh] += expf(leaky(es[sn * NHEAD + hh] + edv[hh]) - mh[hh]);
    }
#pragma unroll
    for (int off = 32; off > 0; off >>= 1)
#pragma unroll
        for (int hh = 0; hh < NHEAD; ++hh) ls[hh] += __shfl_xor(ls[hh], off);
    if (lane == 0)
#pragma unroll
        for (int hh = 0; hh < NHEAD; ++hh) sred[wid][hh] = ls[hh];
    __syncthreads();
    if (t < NHEAD)
        den[t] = sred[0][t] + sred[1][t] + sred[2][t] + sred[3][t] + expf(vself[t] - m[t]);
    __syncthreads();
    float inv[NHEAD];
#pragma unroll
    for (int hh = 0; hh < NHEAD; ++hh) inv[hh] = 1.f / (den[hh] + 1e-16f);

    int d0 = t, d1 = t + 256;
    int h0 = t >> 7, h1 = h0 + 2;
    float acc0, acc1;
    {
        float a0 = expf(vself[h0] - mh[h0]) * inv[h0];
        float a1 = expf(vself[h1] - mh[h1]) * inv[h1];
        acc0 = a0 * h[(long)n * HD + d0];
        acc1 = a1 * h[(long)n * HD + d1];
    }
    __shared__ float alph[64 * NHEAD];
    for (int base = s0; base < s1; base += 64) {
        int cnt = min(64, s1 - base);
        if (t < cnt * NHEAD) {
            int e = t >> 2, hh = t & 3;
            int sn = col[base + e];
            float v = leaky(es[sn * NHEAD + hh] + edv[hh]);
            alph[(e << 2) | hh] = expf(v - mh[hh]) * inv[hh];
        }
        __syncthreads();
        for (int e = 0; e < cnt; ++e) {
            int sn = col[base + e];
            const float* hs = h + (long)sn * HD;
            acc0 += alph[(e << 2) | h0] * hs[d0];
            acc1 += alph[(e << 2) | h1] * hs[d1];
        }
        __syncthreads();
    }

    if (concat) {
        out[(long)n * HD + d0] = acc0 + bias[d0];
        out[(long)n * HD + d1] = acc1 + bias[d1];
    } else {
        __shared__ float accs[HD];
        accs[d0] = acc0;
        accs[d1] = acc1;
        __syncthreads();
        if (t < DDIM)
            out[(long)n * DDIM + t] =
                (accs[t] + accs[t + 128] + accs[t + 256] + accs[t + 384]) * 0.25f + bias[t];
    }
}

// ---------------- BatchNorm ----------------
__global__ __launch_bounds__(256) void bn_stats(const float* __restrict__ x,
                                                float* __restrict__ sums, long total, int C) {
    long gid = (long)blockIdx.x * blockDim.x + threadIdx.x;
    long stride = (long)gridDim.x * blockDim.x;  // multiple of C
    int c = (int)(gid % C);
    float s = 0.f, s2 = 0.f;
    for (long i = gid; i < total; i += stride) {
        float v = x[i];
        s += v; s2 += v * v;
    }
    atomicAdd(&sums[c], s);
    atomicAdd(&sums[C + c], s2);
}

__global__ void bn_finalize(const float* __restrict__ sums, const float* __restrict__ g,
                            const float* __restrict__ be, float* __restrict__ ab,
                            float invN, int C) {
    int c = blockIdx.x * blockDim.x + threadIdx.x;
    if (c < C) {
        float mean = sums[c] * invN;
        float var = sums[C + c] * invN - mean * mean;
        float sc = g[c] * rsqrtf(var + BN_EPS);
        ab[c] = sc;
        ab[C + c] = be[c] - mean * sc;
    }
}

__global__ __launch_bounds__(256) void bn_apply_relu(const float* __restrict__ x,
                                                     const float* __restrict__ ab,
                                                     float* __restrict__ y, long total, int C) {
    long gid = (long)blockIdx.x * blockDim.x + threadIdx.x;
    long stride = (long)gridDim.x * blockDim.x;
    for (long i = gid; i < total; i += stride) {
        int c = (int)(i % C);
        y[i] = fmaxf(0.f, x[i] * ab[c] + ab[C + c]);
    }
}

// ---------------- residue -> SSE pooling ----------------
__global__ void count_res(const int* __restrict__ sid, float* __restrict__ cnt, int Nr) {
    int i = blockIdx.x * blockDim.x + threadIdx.x;
    if (i < Nr) atomicAdd(&cnt[sid[i]], 1.f);
}

__global__ __launch_bounds__(256) void pool_res(const float* __restrict__ x,
                                                const int* __restrict__ sid,
                                                float* __restrict__ pooled, int Nr) {
    long total = (long)Nr * DDIM;
    long stride = (long)gridDim.x * blockDim.x;
    for (long i = (long)blockIdx.x * blockDim.x + threadIdx.x; i < total; i += stride) {
        int n = (int)(i / DDIM), c = (int)(i % DDIM);
        atomicAdd(&pooled[(long)sid[n] * DDIM + c], x[i]);
    }
}

__global__ void build_xsse(const float* __restrict__ pooled, const float* __restrict__ cnt,
                           const int* __restrict__ sstype, float* __restrict__ xsse, int Ns) {
    int i = blockIdx.x * blockDim.x + threadIdx.x;
    if (i >= Ns * SSEIN) return;
    int s = i / SSEIN, j = i % SSEIN;
    float c = cnt[s];
    float v;
    if (j < DDIM) v = pooled[(long)s * DDIM + j] / fmaxf(c, 1.f);
    else if (j < DDIM + 3) v = (sstype[s] == (j - DDIM)) ? 1.f : 0.f;
    else v = c / (float)NRES;
    xsse[i] = v;
}

// ---------------- SSE -> domain pooling ----------------
__global__ void pool_dom(const float* __restrict__ x, float* __restrict__ xdom) {
    int d = blockIdx.x, c = threadIdx.x;
    int spd = NSSE / NDOM;
    int r0 = d * spd;
    int r1 = (d == NDOM - 1) ? NSSE : r0 + spd;
    float acc = 0.f;
    for (int r = r0; r < r1; ++r) acc += x[(long)r * DDIM + c];
    xdom[d * DDIM + c] = acc / (float)(r1 - r0);
}

// ---------------- domain GCN ----------------
__global__ __launch_bounds__(256) void gcn_prep(const int* __restrict__ src,
                                                const int* __restrict__ dst, int E,
                                                float* __restrict__ dis) {
    __shared__ float degL[NDOM];
    int t = threadIdx.x;
    if (t < NDOM) degL[t] = 1.f;
    __syncthreads();
    for (int e = t; e < E; e += blockDim.x) atomicAdd(&degL[dst[e]], 1.f);
    __syncthreads();
    if (t < NDOM) dis[t] = rsqrtf(fmaxf(degL[t], 1e-12f));
}

__global__ void gcn_agg(const float* __restrict__ hdom, const int* __restrict__ src,
                        const int* __restrict__ dst, int E, const float* __restrict__ dis,
                        const float* __restrict__ bd, float* __restrict__ outd) {
    int n = blockIdx.x, c = threadIdx.x;
    float dn = dis[n];
    float acc = dn * dn * hdom[n * OUTD + c];
    for (int e = 0; e < E; ++e)
        if (dst[e] == n) acc += dis[src[e]] * dn * hdom[src[e] * OUTD + c];
    outd[n * OUTD + c] = acc + bd[c];
}

__global__ void bn_small_relu(const float* __restrict__ x, const float* __restrict__ g,
                              const float* __restrict__ be, float* __restrict__ y,
                              int N, int C) {
    int c = threadIdx.x;
    if (c >= C) return;
    float s = 0.f, s2 = 0.f;
    for (int r = 0; r < N; ++r) {
        float v = x[r * C + c];
        s += v; s2 += v * v;
    }
    float mean = s / N;
    float var = s2 / N - mean * mean;
    float sc = g[c] * rsqrtf(var + BN_EPS);
    float sh = be[c] - mean * sc;
    for (int r = 0; r < N; ++r) y[r * C + c] = fmaxf(0.f, x[r * C + c] * sc + sh);
}

// ---------------- readout ----------------
__global__ void col_mean(const float* __restrict__ x, float* __restrict__ out, int N, int C) {
    int c = threadIdx.x;
    if (c >= C) return;
    float s = 0.f;
    for (int r = 0; r < N; ++r) s += x[(long)r * C + c];
    out[c] = s / (float)N;
}

__global__ __launch_bounds__(256) void readout(const float* __restrict__ sse_global,
                                               const float* __restrict__ xdom_bn,
                                               const float* __restrict__ Wproj,
                                               const float* __restrict__ bproj,
                                               const float* __restrict__ Wread,
                                               const float* __restrict__ bread,
                                               float* __restrict__ out) {
    int c = threadIdx.x;
    __shared__ float v[2 * OUTD];
    float s = bproj[c];
    for (int k = 0; k < DDIM; ++k) s += sse_global[k] * Wproj[k * OUTD + c];
    v[c] = s;
    float dm = 0.f;
    for (int r = 0; r < NDOM; ++r) dm += xdom_bn[r * OUTD + c];
    v[OUTD + c] = dm / (float)NDOM;
    __syncthreads();
    float o = bread[c];
    for (int k = 0; k < 2 * OUTD; ++k) o += v[k] * Wread[k * OUTD + c];
    __shared__ float sq[256];
    sq[c] = o * o;
    __syncthreads();
    for (int off = 128; off > 0; off >>= 1) {
        if (c < off) sq[c] += sq[c + off];
        __syncthreads();
    }
    float scale = 1.f / fmaxf(sqrtf(sq[0]), 1e-12f);
    out[c] = o * scale;
}

// ---------------- launcher ----------------
extern "C" void kernel_launch(void* const* d_in, const int* in_sizes, int n_in,
                              void* d_out, int out_size, void* d_ws, size_t ws_size,
                              hipStream_t stream) {
    const float* x_res = (const float*)d_in[0];
    const int* ei_res = (const int*)d_in[1];
    const int* ei_sse = (const int*)d_in[2];
    const int* ei_dom = (const int*)d_in[3];
    const int* res_sse_id = (const int*)d_in[4];
    const int* sse_ss = (const int*)d_in[5];
    const int E_res = in_sizes[1] / 2;
    const int E_sse = in_sizes[2] / 2;
    const int E_dom = in_sizes[3] / 2;
    const int Nr = in_sizes[4];
    const int Ns = in_sizes[5];
    const float* W1 = (const float*)d_in[7];
    const float* asrc1 = (const float*)d_in[8];
    const float* adst1 = (const float*)d_in[9];
    const float* b1 = (const float*)d_in[10];
    const float* g1 = (const float*)d_in[11];
    const float* be1 = (const float*)d_in[12];
    const float* W2 = (const float*)d_in[13];
    const float* asrc2 = (const float*)d_in[14];
    const float* adst2 = (const float*)d_in[15];
    const float* b2 = (const float*)d_in[16];
    const float* g2 = (const float*)d_in[17];
    const float* be2 = (const float*)d_in[18];
    const float* Ws = (const float*)d_in[19];
    const float* asrcs = (const float*)d_in[20];
    const float* adsts = (const float*)d_in[21];
    const float* bs = (const float*)d_in[22];
    const float* gs = (const float*)d_in[23];
    const float* bes = (const float*)d_in[24];
    const float* Wd = (const float*)d_in[25];
    const float* bd = (const float*)d_in[26];
    const float* gd = (const float*)d_in[27];
    const float* bed = (const float*)d_in[28];
    const float* Wproj = (const float*)d_in[29];
    const float* bproj = (const float*)d_in[30];
    const float* Wread = (const float*)d_in[31];
    const float* bread = (const float*)d_in[32];

    // ---- workspace layout: clamp pointers, track unclamped need for fallback decision ----
    char* w = (char*)d_ws;
    size_t off = 0, need = 0;
    auto alloc = [&](size_t bytes) -> char* {
        char* p = w + off;
        size_t inc = (bytes + 255) & ~(size_t)255;
        need += inc;
        if (off + inc > ws_size) inc = (off < ws_size) ? (ws_size - off) : 0;
        off += inc;
        return p;
    };
    float* A     = (float*)alloc((size_t)Nr * HD * 4);   // h1 / h2
    float* Bb    = (float*)alloc((size_t)Nr * HD * 4);   // gat1 out (pre-BN)
    float* C2    = (float*)alloc((size_t)Nr * DDIM * 4);
    float* es    = (float*)alloc((size_t)Nr * NHEAD * 4);
    float* ed    = (float*)alloc((size_t)Nr * NHEAD * 4);
    int* rp_res  = (int*)alloc((size_t)(Nr + 1) * 4);
    int* col_res = (int*)alloc((size_t)E_res * 4);
    int* rp_sse  = (int*)alloc((size_t)(Ns + 1) * 4);
    int* col_sse = (int*)alloc((size_t)E_sse * 4);
    float* xsse  = (float*)alloc((size_t)Ns * SSEIN * 4);
    float* h_s   = (float*)alloc((size_t)Ns * HD * 4);
    float* xs_o  = (float*)alloc((size_t)Ns * DDIM * 4);
    float* xdom  = (float*)alloc((size_t)NDOM * DDIM * 4);
    float* hdom  = (float*)alloc((size_t)NDOM * OUTD * 4);
    float* gdom  = (float*)alloc((size_t)NDOM * OUTD * 4);
    float* gdom2 = (float*)alloc((size_t)NDOM * OUTD * 4);
    float* dis   = (float*)alloc((size_t)NDOM * 4);
    float* sse_g = (float*)alloc((size_t)DDIM * 4);
    float* ab1   = (float*)alloc((size_t)2 * HD * 4);
    float* ab2   = (float*)alloc((size_t)2 * DDIM * 4);
    float* ab_s  = (float*)alloc((size_t)2 * DDIM * 4);
    // zeroed region (single memset)
    char* zbase = w + off;
    int* deg_res  = (int*)alloc((size_t)Nr * 4);
    int* cur_res  = (int*)alloc((size_t)Nr * 4);
    int* deg_sse  = (int*)alloc((size_t)Ns * 4);
    int* cur_sse  = (int*)alloc((size_t)Ns * 4);
    float* cnt    = (float*)alloc((size_t)Ns * 4);
    float* pooled = (float*)alloc((size_t)Ns * DDIM * 4);
    float* bsum1  = (float*)alloc((size_t)2 * HD * 4);
    float* bsum2  = (float*)alloc((size_t)2 * DDIM * 4);
    float* bsum_s = (float*)alloc((size_t)2 * DDIM * 4);
    size_t zbytes = (size_t)((w + off) - zbase);
    // f16 split buffers (allocated last so base layout matches fallback exactly)
    f16* A1hi  = (f16*)alloc((size_t)Nr * KP1 * 2);
    f16* A1lo  = (f16*)alloc((size_t)Nr * KP1 * 2);
    f16* W1thi = (f16*)alloc((size_t)HD * KP1 * 2);
    f16* W1tlo = (f16*)alloc((size_t)HD * KP1 * 2);
    f16* W2thi = (f16*)alloc((size_t)HD * HD * 2);
    f16* W2tlo = (f16*)alloc((size_t)HD * HD * 2);
    // A2 aliases A1's region (disjoint lifetimes: A1 dead after GEMM1; A2 written post-BN1)
    f16* A2hi = A1hi;
    f16* A2lo = A1hi + (size_t)Nr * HD;
    bool use_mfma = (need <= ws_size);
    (void)n_in; (void)out_size;

    hipMemsetAsync(zbase, 0, zbytes, stream);

    const int* src_res = ei_res;
    const int* dst_res = ei_res + E_res;
    const int* src_sse = ei_sse;
    const int* dst_sse = ei_sse + E_sse;
    const int* src_dom = ei_dom;
    const int* dst_dom = ei_dom + E_dom;

    // CSR builds
    count_deg<<<(E_res + 255) / 256, 256, 0, stream>>>(dst_res, E_res, deg_res);
    exclusive_scan<<<1, 256, 0, stream>>>(deg_res, rp_res, Nr);
    csr_fill<<<(E_res + 255) / 256, 256, 0, stream>>>(src_res, dst_res, E_res, rp_res, cur_res, col_res);
    count_deg<<<(E_sse + 255) / 256, 256, 0, stream>>>(dst_sse, E_sse, deg_sse);
    exclusive_scan<<<1, 256, 0, stream>>>(deg_sse, rp_sse, Ns);
    csr_fill<<<(E_sse + 255) / 256, 256, 0, stream>>>(src_sse, dst_sse, E_sse, rp_sse, cur_sse, col_sse);

    int mrows = (Nr + 127) / 128;

    // ---- Level 1, GAT1 (concat) ----
    if (use_mfma) {
        split_rows<<<2048, 256, 0, stream>>>(x_res, A1hi, A1lo, Nr, FIN, KP1);
        split_w_t<<<512, 256, 0, stream>>>(W1, W1thi, W1tlo, FIN, HD, KP1);
        split_w_t<<<512, 256, 0, stream>>>(W2, W2thi, W2tlo, HD, HD, HD);
        mfma_gemm<<<dim3(HD / 64, mrows), 256, 0, stream>>>(A1hi, A1lo, W1thi, W1tlo, A, Nr, HD, KP1);
    } else {
        sgemm64<<<dim3(HD / 64, (Nr + 63) / 64), 256, 0, stream>>>(x_res, W1, A, Nr, HD, FIN);
    }
    att_scores<<<(Nr + 3) / 4, 256, 0, stream>>>(A, asrc1, adst1, es, ed, Nr);
    gat_aggregate<<<Nr, 256, 0, stream>>>(A, es, ed, rp_res, col_res, b1, Bb, Nr, 1);
    bn_stats<<<512, 256, 0, stream>>>(Bb, bsum1, (long)Nr * HD, HD);
    bn_finalize<<<2, 256, 0, stream>>>(bsum1, g1, be1, ab1, 1.f / Nr, HD);

    // ---- Level 1, GAT2 (mean heads) ----
    if (use_mfma) {
        bn_apply_split<<<2048, 256, 0, stream>>>(Bb, ab1, A2hi, A2lo, (long)Nr * HD, HD);
        mfma_gemm<<<dim3(HD / 64, mrows), 256, 0, stream>>>(A2hi, A2lo, W2thi, W2tlo, A, Nr, HD, HD);
    } else {
        bn_apply_relu<<<2048, 256, 0, stream>>>(Bb, ab1, Bb, (long)Nr * HD, HD);
        sgemm64<<<dim3(HD / 64, (Nr + 63) / 64), 256, 0, stream>>>(Bb, W2, A, Nr, HD, HD);
    }
    att_scores<<<(Nr + 3) / 4, 256, 0, stream>>>(A, asrc2, adst2, es, ed, Nr);
    gat_aggregate<<<Nr, 256, 0, stream>>>(A, es, ed, rp_res, col_res, b2, C2, Nr, 0);
    bn_stats<<<512, 256, 0, stream>>>(C2, bsum2, (long)Nr * DDIM, DDIM);
    bn_finalize<<<1, 128, 0, stream>>>(bsum2, g2, be2, ab2, 1.f / Nr, DDIM);
    bn_apply_relu<<<2048, 256, 0, stream>>>(C2, ab2, C2, (long)Nr * DDIM, DDIM);

    // ---- pool residues -> SSE ----
    count_res<<<(Nr + 255) / 256, 256, 0, stream>>>(res_sse_id, cnt, Nr);
    pool_res<<<2048, 256, 0, stream>>>(C2, res_sse_id, pooled, Nr);
    build_xsse<<<(Ns * SSEIN + 255) / 256, 256, 0, stream>>>(pooled, cnt, sse_ss, xsse, Ns);

    // ---- Level 2: SSE GAT ----
    sgemm64<<<dim3(HD / 64, (Ns + 63) / 64), 256, 0, stream>>>(xsse, Ws, h_s, Ns, HD, SSEIN);
    att_scores<<<(Ns + 3) / 4, 256, 0, stream>>>(h_s, asrcs, adsts, es, ed, Ns);
    gat_aggregate<<<Ns, 256, 0, stream>>>(h_s, es, ed, rp_sse, col_sse, bs, xs_o, Ns, 0);
    bn_stats<<<512, 256, 0, stream>>>(xs_o, bsum_s, (long)Ns * DDIM, DDIM);
    bn_finalize<<<1, 128, 0, stream>>>(bsum_s, gs, bes, ab_s, 1.f / Ns, DDIM);
    bn_apply_relu<<<512, 256, 0, stream>>>(xs_o, ab_s, xs_o, (long)Ns * DDIM, DDIM);

    // ---- pool SSE -> domains; GCN; BN ----
    pool_dom<<<NDOM, DDIM, 0, stream>>>(xs_o, xdom);
    sgemm64<<<dim3(OUTD / 64, 1), 256, 0, stream>>>(xdom, Wd, hdom, NDOM, OUTD, DDIM);
    gcn_prep<<<1, 256, 0, stream>>>(src_dom, dst_dom, E_dom, dis);
    gcn_agg<<<NDOM, OUTD, 0, stream>>>(hdom, src_dom, dst_dom, E_dom, dis, bd, gdom);
    bn_small_relu<<<1, OUTD, 0, stream>>>(gdom, gd, bed, gdom2, NDOM, OUTD);

    // ---- readout ----
    col_mean<<<1, DDIM, 0, stream>>>(xs_o, sse_g, Ns, DDIM);
    readout<<<1, OUTD, 0, stream>>>(sse_g, gdom2, Wproj, bproj, Wread, bread, (float*)d_out);
}

// Round 4
// 1040.250 us; speedup vs baseline: 1.9168x; 1.3625x over previous
//
#include <hip/hip_runtime.h>
#include <math.h>

// ---------------- problem constants (match reference) ----------------
#define NRES   20000
#define NSSE   2000
#define NDOM   40
#define FIN    1302
#define NHEAD  4
#define DDIM   128
#define HD     512      // NHEAD*DDIM
#define OUTD   256
#define SSEIN  132      // DDIM+3+1
#define BN_EPS 1e-5f
#define KP1    1312     // FIN padded to multiple of 32

typedef _Float16 f16;
typedef __attribute__((ext_vector_type(8))) _Float16 f16x8;
typedef __attribute__((ext_vector_type(4))) float f32x4;

__device__ __forceinline__ float leaky(float v) { return v > 0.f ? v : 0.2f * v; }

// ---------------- f32 -> (hi,lo) f16 split, row layout [M][Kpad], zero-padded ----------
__global__ __launch_bounds__(256) void split_rows(const float* __restrict__ X,
                                                  f16* __restrict__ hi, f16* __restrict__ lo,
                                                  int M, int K, int Kpad) {
    long slots = (long)M * (Kpad >> 3);
    long stride = (long)gridDim.x * blockDim.x;
    for (long s = (long)blockIdx.x * blockDim.x + threadIdx.x; s < slots; s += stride) {
        int m = (int)(s / (Kpad >> 3));
        int kc = (int)(s % (Kpad >> 3)) << 3;
        f16x8 h, l;
#pragma unroll
        for (int j = 0; j < 8; ++j) {
            int k = kc + j;
            float v = (k < K) ? X[(long)m * K + k] : 0.f;
            f16 hh = (f16)v;
            h[j] = hh;
            l[j] = (f16)(v - (float)hh);
        }
        long o = ((long)m * Kpad + kc);
        *(f16x8*)&hi[o] = h;
        *(f16x8*)&lo[o] = l;
    }
}

// ---------------- W[K][N] f32 -> transposed split [N][Kpad] --------------------------
__global__ __launch_bounds__(256) void split_w_t(const float* __restrict__ W,
                                                 f16* __restrict__ hi, f16* __restrict__ lo,
                                                 int K, int N, int Kpad) {
    long total = (long)N * Kpad;
    long stride = (long)gridDim.x * blockDim.x;
    for (long i = (long)blockIdx.x * blockDim.x + threadIdx.x; i < total; i += stride) {
        int n = (int)(i / Kpad), k = (int)(i % Kpad);
        float v = (k < K) ? W[(long)k * N + n] : 0.f;
        f16 h = (f16)v;
        hi[i] = h;
        lo[i] = (f16)(v - (float)h);
    }
}

// ---------------- BN apply + ReLU fused with hi/lo split (for GEMM2 input) -----------
__global__ __launch_bounds__(256) void bn_apply_split(const float* __restrict__ x,
                                                      const float* __restrict__ ab,
                                                      f16* __restrict__ hi, f16* __restrict__ lo,
                                                      long total, int C) {
    long stride = (long)gridDim.x * blockDim.x;
    for (long i = (long)blockIdx.x * blockDim.x + threadIdx.x; i < total; i += stride) {
        int c = (int)(i % C);
        float v = fmaxf(0.f, x[i] * ab[c] + ab[C + c]);
        f16 h = (f16)v;
        hi[i] = h;
        lo[i] = (f16)(v - (float)h);
    }
}

// ---------------- MFMA GEMM: C[M][N] = A @ B via f16 hi/lo 3-pass --------------------
__global__ __launch_bounds__(256) void mfma_gemm(const f16* __restrict__ Ahi,
                                                 const f16* __restrict__ Alo,
                                                 const f16* __restrict__ Bthi,
                                                 const f16* __restrict__ Btlo,
                                                 float* __restrict__ C,
                                                 int M, int N, int Kpad) {
    __shared__ f16 As[2][128][40];  // [hi/lo][row][k]  pitch 40 (80B) -> 2-way bank alias only
    __shared__ f16 Bs[2][64][40];   // [hi/lo][col][k]
    int t = threadIdx.x;
    int w = t >> 6, l = t & 63;
    int wr = w >> 1, wc = w & 1;
    int row0 = blockIdx.y * 128, col0 = blockIdx.x * 64;

    f32x4 acc[4][2] = {};

    for (int k0 = 0; k0 < Kpad; k0 += 32) {
#pragma unroll
        for (int r = 0; r < 2; ++r) {
            int s = t + (r << 8);
            int row = s >> 2, kc = (s & 3) << 3;
            int grow = row0 + row; if (grow >= M) grow = M - 1;  // safe read; result discarded
            long gi = (long)grow * Kpad + k0 + kc;
            *(f16x8*)&As[0][row][kc] = *(const f16x8*)&Ahi[gi];
            *(f16x8*)&As[1][row][kc] = *(const f16x8*)&Alo[gi];
        }
        {
            int col = t >> 2, kc = (t & 3) << 3;
            long gi = (long)(col0 + col) * Kpad + k0 + kc;
            *(f16x8*)&Bs[0][col][kc] = *(const f16x8*)&Bthi[gi];
            *(f16x8*)&Bs[1][col][kc] = *(const f16x8*)&Btlo[gi];
        }
        __syncthreads();

        int lr = l & 15, ks = (l >> 4) << 3;
        f16x8 ah[4], al[4], bh[2], bl[2];
#pragma unroll
        for (int fi = 0; fi < 4; ++fi) {
            int row = wr * 64 + fi * 16 + lr;
            ah[fi] = *(const f16x8*)&As[0][row][ks];
            al[fi] = *(const f16x8*)&As[1][row][ks];
        }
#pragma unroll
        for (int fj = 0; fj < 2; ++fj) {
            int col = wc * 32 + fj * 16 + lr;
            bh[fj] = *(const f16x8*)&Bs[0][col][ks];
            bl[fj] = *(const f16x8*)&Bs[1][col][ks];
        }
#pragma unroll
        for (int fi = 0; fi < 4; ++fi)
#pragma unroll
            for (int fj = 0; fj < 2; ++fj) {
                acc[fi][fj] = __builtin_amdgcn_mfma_f32_16x16x32_f16(ah[fi], bh[fj], acc[fi][fj], 0, 0, 0);
                acc[fi][fj] = __builtin_amdgcn_mfma_f32_16x16x32_f16(ah[fi], bl[fj], acc[fi][fj], 0, 0, 0);
                acc[fi][fj] = __builtin_amdgcn_mfma_f32_16x16x32_f16(al[fi], bh[fj], acc[fi][fj], 0, 0, 0);
            }
        __syncthreads();
    }
    // epilogue: C/D layout (m89-verified): col = lane&15, row = (lane>>4)*4 + reg
    int lr = l & 15, lq = l >> 4;
#pragma unroll
    for (int fi = 0; fi < 4; ++fi)
#pragma unroll
        for (int fj = 0; fj < 2; ++fj)
#pragma unroll
            for (int r = 0; r < 4; ++r) {
                int row = row0 + wr * 64 + fi * 16 + lq * 4 + r;
                int col = col0 + wc * 32 + fj * 16 + lr;
                if (row < M) C[(long)row * N + col] = acc[fi][fj][r];
            }
}

// ---------------- generic tiled f32 GEMM (small GEMMs + fallback) ----------------
__global__ __launch_bounds__(256) void sgemm64(const float* __restrict__ A,
                                               const float* __restrict__ B,
                                               float* __restrict__ C,
                                               int M, int N, int K) {
    __shared__ float As[16][68];
    __shared__ float Bs[16][68];
    int t = threadIdx.x;
    int tx = t & 15, ty = t >> 4;
    int row0 = blockIdx.y * 64, col0 = blockIdx.x * 64;
    float acc[4][4] = {};
    for (int k0 = 0; k0 < K; k0 += 16) {
#pragma unroll
        for (int i = 0; i < 4; ++i) {
            int idx = t * 4 + i;
            int r = idx >> 4, kk = idx & 15;
            int gr = row0 + r, gk = k0 + kk;
            As[kk][r] = (gr < M && gk < K) ? A[(long)gr * K + gk] : 0.f;
        }
#pragma unroll
        for (int i = 0; i < 4; ++i) {
            int idx = t * 4 + i;
            int kk = idx >> 6, c = idx & 63;
            int gk = k0 + kk, gc = col0 + c;
            Bs[kk][c] = (gk < K && gc < N) ? B[(long)gk * N + gc] : 0.f;
        }
        __syncthreads();
#pragma unroll
        for (int kk = 0; kk < 16; ++kk) {
            float a[4], b[4];
#pragma unroll
            for (int i = 0; i < 4; ++i) a[i] = As[kk][ty * 4 + i];
#pragma unroll
            for (int j = 0; j < 4; ++j) b[j] = Bs[kk][tx * 4 + j];
#pragma unroll
            for (int i = 0; i < 4; ++i)
#pragma unroll
                for (int j = 0; j < 4; ++j) acc[i][j] += a[i] * b[j];
        }
        __syncthreads();
    }
#pragma unroll
    for (int i = 0; i < 4; ++i) {
        int r = row0 + ty * 4 + i;
        if (r >= M) continue;
#pragma unroll
        for (int j = 0; j < 4; ++j) {
            int c = col0 + tx * 4 + j;
            if (c < N) C[(long)r * N + c] = acc[i][j];
        }
    }
}

// ---------------- CSR build ----------------
__global__ void count_deg(const int* __restrict__ dst, int E, int* __restrict__ deg) {
    int i = blockIdx.x * blockDim.x + threadIdx.x;
    if (i < E) atomicAdd(&deg[dst[i]], 1);
}

__global__ __launch_bounds__(256) void exclusive_scan(const int* __restrict__ deg,
                                                      int* __restrict__ row_ptr, int N) {
    __shared__ int part[256];
    __shared__ int base[257];
    int t = threadIdx.x;
    int chunk = (N + 255) / 256;
    int lo = t * chunk, hi = min(lo + chunk, N);
    if (lo > N) lo = N;
    if (hi > N) hi = N;
    int s = 0;
    for (int i = lo; i < hi; ++i) s += deg[i];
    part[t] = s;
    __syncthreads();
    if (t == 0) {
        int r = 0;
        for (int i = 0; i < 256; ++i) { base[i] = r; r += part[i]; }
        base[256] = r;
    }
    __syncthreads();
    int run = base[t];
    for (int i = lo; i < hi; ++i) { row_ptr[i] = run; run += deg[i]; }
    if (t == 0) row_ptr[N] = base[256];
}

__global__ void csr_fill(const int* __restrict__ src, const int* __restrict__ dst, int E,
                         const int* __restrict__ row_ptr, int* __restrict__ cursor,
                         int* __restrict__ col) {
    int i = blockIdx.x * blockDim.x + threadIdx.x;
    if (i < E) {
        int d = dst[i];
        int p = row_ptr[d] + atomicAdd(&cursor[d], 1);
        col[p] = src[i];
    }
}

// ---------------- attention scores ----------------
__global__ __launch_bounds__(256) void att_scores(const float* __restrict__ h,
                                                  const float* __restrict__ asrc,
                                                  const float* __restrict__ adst,
                                                  float* __restrict__ es,
                                                  float* __restrict__ ed, int N) {
    int wid = threadIdx.x >> 6, lane = threadIdx.x & 63;
    int n = blockIdx.x * 4 + wid;
    if (n >= N) return;
    const float* hr = h + (long)n * HD;
    float ps[NHEAD], pd[NHEAD];
#pragma unroll
    for (int hh = 0; hh < NHEAD; ++hh) {
        float s = 0.f, d = 0.f;
#pragma unroll
        for (int j = 0; j < 2; ++j) {
            int c = hh * DDIM + lane + j * 64;
            float v = hr[c];
            s += v * asrc[c];
            d += v * adst[c];
        }
        ps[hh] = s; pd[hh] = d;
    }
#pragma unroll
    for (int off = 32; off > 0; off >>= 1) {
#pragma unroll
        for (int hh = 0; hh < NHEAD; ++hh) {
            ps[hh] += __shfl_xor(ps[hh], off);
            pd[hh] += __shfl_xor(pd[hh], off);
        }
    }
    if (lane == 0) {
#pragma unroll
        for (int hh = 0; hh < NHEAD; ++hh) {
            es[n * NHEAD + hh] = ps[hh];
            ed[n * NHEAD + hh] = pd[hh];
        }
    }
}

// ---------------- GAT aggregation ----------------
__global__ __launch_bounds__(256) void gat_aggregate(const float* __restrict__ h,
                                                     const float* __restrict__ es,
                                                     const float* __restrict__ ed,
                                                     const int* __restrict__ row_ptr,
                                                     const int* __restrict__ col,
                                                     const float* __restrict__ bias,
                                                     float* __restrict__ out,
                                                     int N, int concat) {
    int n = blockIdx.x;
    int t = threadIdx.x;
    int lane = t & 63, wid = t >> 6;
    int s0 = row_ptr[n], s1 = row_ptr[n + 1];

    float edv[NHEAD], vself[NHEAD];
#pragma unroll
    for (int hh = 0; hh < NHEAD; ++hh) {
        edv[hh] = ed[n * NHEAD + hh];
        vself[hh] = leaky(es[n * NHEAD + hh] + edv[hh]);
    }
    __shared__ float sred[4][NHEAD];
    __shared__ float m[NHEAD], den[NHEAD];

    float lm[NHEAD] = {-1e30f, -1e30f, -1e30f, -1e30f};
    for (int k = s0 + t; k < s1; k += 256) {
        int sn = col[k];
#pragma unroll
        for (int hh = 0; hh < NHEAD; ++hh)
            lm[hh] = fmaxf(lm[hh], leaky(es[sn * NHEAD + hh] + edv[hh]));
    }
#pragma unroll
    for (int off = 32; off > 0; off >>= 1)
#pragma unroll
        for (int hh = 0; hh < NHEAD; ++hh) lm[hh] = fmaxf(lm[hh], __shfl_xor(lm[hh], off));
    if (lane == 0)
#pragma unroll
        for (int hh = 0; hh < NHEAD; ++hh) sred[wid][hh] = lm[hh];
    __syncthreads();
    if (t < NHEAD) {
        float mm = vself[t];
#pragma unroll
        for (int w = 0; w < 4; ++w) mm = fmaxf(mm, sred[w][t]);
        m[t] = mm;
    }
    __syncthreads();
    float mh[NHEAD];
#pragma unroll
    for (int hh = 0; hh < NHEAD; ++hh) mh[hh] = m[hh];

    float ls[NHEAD] = {0.f, 0.f, 0.f, 0.f};
    for (int k = s0 + t; k < s1; k += 256) {
        int sn = col[k];
#pragma unroll
        for (int hh = 0; hh < NHEAD; ++hh)
            ls[hh] += expf(leaky(es[sn * NHEAD + hh] + edv[hh]) - mh[hh]);
    }
#pragma unroll
    for (int off = 32; off > 0; off >>= 1)
#pragma unroll
        for (int hh = 0; hh < NHEAD; ++hh) ls[hh] += __shfl_xor(ls[hh], off);
    if (lane == 0)
#pragma unroll
        for (int hh = 0; hh < NHEAD; ++hh) sred[wid][hh] = ls[hh];
    __syncthreads();
    if (t < NHEAD)
        den[t] = sred[0][t] + sred[1][t] + sred[2][t] + sred[3][t] + expf(vself[t] - m[t]);
    __syncthreads();
    float inv[NHEAD];
#pragma unroll
    for (int hh = 0; hh < NHEAD; ++hh) inv[hh] = 1.f / (den[hh] + 1e-16f);

    int d0 = t, d1 = t + 256;
    int h0 = t >> 7, h1 = h0 + 2;
    float acc0, acc1;
    {
        float a0 = expf(vself[h0] - mh[h0]) * inv[h0];
        float a1 = expf(vself[h1] - mh[h1]) * inv[h1];
        acc0 = a0 * h[(long)n * HD + d0];
        acc1 = a1 * h[(long)n * HD + d1];
    }
    __shared__ float alph[64 * NHEAD];
    for (int base = s0; base < s1; base += 64) {
        int cnt = min(64, s1 - base);
        if (t < cnt * NHEAD) {
            int e = t >> 2, hh = t & 3;
            int sn = col[base + e];
            float v = leaky(es[sn * NHEAD + hh] + edv[hh]);
            alph[(e << 2) | hh] = expf(v - mh[hh]) * inv[hh];
        }
        __syncthreads();
        for (int e = 0; e < cnt; ++e) {
            int sn = col[base + e];
            const float* hs = h + (long)sn * HD;
            acc0 += alph[(e << 2) | h0] * hs[d0];
            acc1 += alph[(e << 2) | h1] * hs[d1];
        }
        __syncthreads();
    }

    if (concat) {
        out[(long)n * HD + d0] = acc0 + bias[d0];
        out[(long)n * HD + d1] = acc1 + bias[d1];
    } else {
        __shared__ float accs[HD];
        accs[d0] = acc0;
        accs[d1] = acc1;
        __syncthreads();
        if (t < DDIM)
            out[(long)n * DDIM + t] =
                (accs[t] + accs[t + 128] + accs[t + 256] + accs[t + 384]) * 0.25f + bias[t];
    }
}

// ---------------- BatchNorm ----------------
__global__ __launch_bounds__(256) void bn_stats(const float* __restrict__ x,
                                                float* __restrict__ sums, long total, int C) {
    long gid = (long)blockIdx.x * blockDim.x + threadIdx.x;
    long stride = (long)gridDim.x * blockDim.x;  // multiple of C
    int c = (int)(gid % C);
    float s = 0.f, s2 = 0.f;
    for (long i = gid; i < total; i += stride) {
        float v = x[i];
        s += v; s2 += v * v;
    }
    atomicAdd(&sums[c], s);
    atomicAdd(&sums[C + c], s2);
}

__global__ void bn_finalize(const float* __restrict__ sums, const float* __restrict__ g,
                            const float* __restrict__ be, float* __restrict__ ab,
                            float invN, int C) {
    int c = blockIdx.x * blockDim.x + threadIdx.x;
    if (c < C) {
        float mean = sums[c] * invN;
        float var = sums[C + c] * invN - mean * mean;
        float sc = g[c] * rsqrtf(var + BN_EPS);
        ab[c] = sc;
        ab[C + c] = be[c] - mean * sc;
    }
}

__global__ __launch_bounds__(256) void bn_apply_relu(const float* __restrict__ x,
                                                     const float* __restrict__ ab,
                                                     float* __restrict__ y, long total, int C) {
    long gid = (long)blockIdx.x * blockDim.x + threadIdx.x;
    long stride = (long)gridDim.x * blockDim.x;
    for (long i = gid; i < total; i += stride) {
        int c = (int)(i % C);
        y[i] = fmaxf(0.f, x[i] * ab[c] + ab[C + c]);
    }
}

// ---------------- residue -> SSE pooling ----------------
__global__ void count_res(const int* __restrict__ sid, float* __restrict__ cnt, int Nr) {
    int i = blockIdx.x * blockDim.x + threadIdx.x;
    if (i < Nr) atomicAdd(&cnt[sid[i]], 1.f);
}

__global__ __launch_bounds__(256) void pool_res(const float* __restrict__ x,
                                                const int* __restrict__ sid,
                                                float* __restrict__ pooled, int Nr) {
    long total = (long)Nr * DDIM;
    long stride = (long)gridDim.x * blockDim.x;
    for (long i = (long)blockIdx.x * blockDim.x + threadIdx.x; i < total; i += stride) {
        int n = (int)(i / DDIM), c = (int)(i % DDIM);
        atomicAdd(&pooled[(long)sid[n] * DDIM + c], x[i]);
    }
}

__global__ void build_xsse(const float* __restrict__ pooled, const float* __restrict__ cnt,
                           const int* __restrict__ sstype, float* __restrict__ xsse, int Ns) {
    int i = blockIdx.x * blockDim.x + threadIdx.x;
    if (i >= Ns * SSEIN) return;
    int s = i / SSEIN, j = i % SSEIN;
    float c = cnt[s];
    float v;
    if (j < DDIM) v = pooled[(long)s * DDIM + j] / fmaxf(c, 1.f);
    else if (j < DDIM + 3) v = (sstype[s] == (j - DDIM)) ? 1.f : 0.f;
    else v = c / (float)NRES;
    xsse[i] = v;
}

// ---------------- SSE -> domain pooling ----------------
__global__ void pool_dom(const float* __restrict__ x, float* __restrict__ xdom) {
    int d = blockIdx.x, c = threadIdx.x;
    int spd = NSSE / NDOM;
    int r0 = d * spd;
    int r1 = (d == NDOM - 1) ? NSSE : r0 + spd;
    float acc = 0.f;
    for (int r = r0; r < r1; ++r) acc += x[(long)r * DDIM + c];
    xdom[d * DDIM + c] = acc / (float)(r1 - r0);
}

// ---------------- domain GCN ----------------
__global__ __launch_bounds__(256) void gcn_prep(const int* __restrict__ src,
                                                const int* __restrict__ dst, int E,
                                                float* __restrict__ dis) {
    __shared__ float degL[NDOM];
    int t = threadIdx.x;
    if (t < NDOM) degL[t] = 1.f;
    __syncthreads();
    for (int e = t; e < E; e += blockDim.x) atomicAdd(&degL[dst[e]], 1.f);
    __syncthreads();
    if (t < NDOM) dis[t] = rsqrtf(fmaxf(degL[t], 1e-12f));
}

__global__ void gcn_agg(const float* __restrict__ hdom, const int* __restrict__ src,
                        const int* __restrict__ dst, int E, const float* __restrict__ dis,
                        const float* __restrict__ bd, float* __restrict__ outd) {
    int n = blockIdx.x, c = threadIdx.x;
    float dn = dis[n];
    float acc = dn * dn * hdom[n * OUTD + c];
    for (int e = 0; e < E; ++e)
        if (dst[e] == n) acc += dis[src[e]] * dn * hdom[src[e] * OUTD + c];
    outd[n * OUTD + c] = acc + bd[c];
}

__global__ void bn_small_relu(const float* __restrict__ x, const float* __restrict__ g,
                              const float* __restrict__ be, float* __restrict__ y,
                              int N, int C) {
    int c = threadIdx.x;
    if (c >= C) return;
    float s = 0.f, s2 = 0.f;
#pragma unroll 8
    for (int r = 0; r < N; ++r) {
        float v = x[r * C + c];
        s += v; s2 += v * v;
    }
    float mean = s / N;
    float var = s2 / N - mean * mean;
    float sc = g[c] * rsqrtf(var + BN_EPS);
    float sh = be[c] - mean * sc;
#pragma unroll 8
    for (int r = 0; r < N; ++r) y[r * C + c] = fmaxf(0.f, x[r * C + c] * sc + sh);
}

// ---------------- parallel column sum (replaces serial col_mean) ----------------
// out must be zeroed; stride is a multiple of C so each thread owns one column.
__global__ __launch_bounds__(256) void col_sum_atomic(const float* __restrict__ x,
                                                      float* __restrict__ out,
                                                      long total, int C) {
    long gid = (long)blockIdx.x * blockDim.x + threadIdx.x;
    long stride = (long)gridDim.x * blockDim.x;  // multiple of C
    int c = (int)(gid % C);
    float s = 0.f;
    for (long i = gid; i < total; i += stride) s += x[i];
    atomicAdd(&out[c], s);
}

// ---------------- readout ----------------
__global__ __launch_bounds__(256) void readout(const float* __restrict__ sse_sum,
                                               float invNs,
                                               const float* __restrict__ xdom_bn,
                                               const float* __restrict__ Wproj,
                                               const float* __restrict__ bproj,
                                               const float* __restrict__ Wread,
                                               const float* __restrict__ bread,
                                               float* __restrict__ out) {
    int c = threadIdx.x;
    __shared__ float v[2 * OUTD];
    float s = 0.f;
#pragma unroll 8
    for (int k = 0; k < DDIM; ++k) s += sse_sum[k] * Wproj[k * OUTD + c];
    v[c] = s * invNs + bproj[c];
    float dm = 0.f;
#pragma unroll 8
    for (int r = 0; r < NDOM; ++r) dm += xdom_bn[r * OUTD + c];
    v[OUTD + c] = dm / (float)NDOM;
    __syncthreads();
    float o = bread[c];
#pragma unroll 8
    for (int k = 0; k < 2 * OUTD; ++k) o += v[k] * Wread[k * OUTD + c];
    __shared__ float sq[256];
    sq[c] = o * o;
    __syncthreads();
    for (int off = 128; off > 0; off >>= 1) {
        if (c < off) sq[c] += sq[c + off];
        __syncthreads();
    }
    float scale = 1.f / fmaxf(sqrtf(sq[0]), 1e-12f);
    out[c] = o * scale;
}

// ---------------- launcher ----------------
extern "C" void kernel_launch(void* const* d_in, const int* in_sizes, int n_in,
                              void* d_out, int out_size, void* d_ws, size_t ws_size,
                              hipStream_t stream) {
    const float* x_res = (const float*)d_in[0];
    const int* ei_res = (const int*)d_in[1];
    const int* ei_sse = (const int*)d_in[2];
    const int* ei_dom = (const int*)d_in[3];
    const int* res_sse_id = (const int*)d_in[4];
    const int* sse_ss = (const int*)d_in[5];
    const int E_res = in_sizes[1] / 2;
    const int E_sse = in_sizes[2] / 2;
    const int E_dom = in_sizes[3] / 2;
    const int Nr = in_sizes[4];
    const int Ns = in_sizes[5];
    const float* W1 = (const float*)d_in[7];
    const float* asrc1 = (const float*)d_in[8];
    const float* adst1 = (const float*)d_in[9];
    const float* b1 = (const float*)d_in[10];
    const float* g1 = (const float*)d_in[11];
    const float* be1 = (const float*)d_in[12];
    const float* W2 = (const float*)d_in[13];
    const float* asrc2 = (const float*)d_in[14];
    const float* adst2 = (const float*)d_in[15];
    const float* b2 = (const float*)d_in[16];
    const float* g2 = (const float*)d_in[17];
    const float* be2 = (const float*)d_in[18];
    const float* Ws = (const float*)d_in[19];
    const float* asrcs = (const float*)d_in[20];
    const float* adsts = (const float*)d_in[21];
    const float* bs = (const float*)d_in[22];
    const float* gs = (const float*)d_in[23];
    const float* bes = (const float*)d_in[24];
    const float* Wd = (const float*)d_in[25];
    const float* bd = (const float*)d_in[26];
    const float* gd = (const float*)d_in[27];
    const float* bed = (const float*)d_in[28];
    const float* Wproj = (const float*)d_in[29];
    const float* bproj = (const float*)d_in[30];
    const float* Wread = (const float*)d_in[31];
    const float* bread = (const float*)d_in[32];

    // ---- workspace layout: clamp pointers, track unclamped need for fallback decision ----
    char* w = (char*)d_ws;
    size_t off = 0, need = 0;
    auto alloc = [&](size_t bytes) -> char* {
        char* p = w + off;
        size_t inc = (bytes + 255) & ~(size_t)255;
        need += inc;
        if (off + inc > ws_size) inc = (off < ws_size) ? (ws_size - off) : 0;
        off += inc;
        return p;
    };
    float* A     = (float*)alloc((size_t)Nr * HD * 4);   // h1 / h2
    float* Bb    = (float*)alloc((size_t)Nr * HD * 4);   // gat1 out (pre-BN)
    float* C2    = (float*)alloc((size_t)Nr * DDIM * 4);
    float* es    = (float*)alloc((size_t)Nr * NHEAD * 4);
    float* ed    = (float*)alloc((size_t)Nr * NHEAD * 4);
    int* rp_res  = (int*)alloc((size_t)(Nr + 1) * 4);
    int* col_res = (int*)alloc((size_t)E_res * 4);
    int* rp_sse  = (int*)alloc((size_t)(Ns + 1) * 4);
    int* col_sse = (int*)alloc((size_t)E_sse * 4);
    float* xsse  = (float*)alloc((size_t)Ns * SSEIN * 4);
    float* h_s   = (float*)alloc((size_t)Ns * HD * 4);
    float* xs_o  = (float*)alloc((size_t)Ns * DDIM * 4);
    float* xdom  = (float*)alloc((size_t)NDOM * DDIM * 4);
    float* hdom  = (float*)alloc((size_t)NDOM * OUTD * 4);
    float* gdom  = (float*)alloc((size_t)NDOM * OUTD * 4);
    float* gdom2 = (float*)alloc((size_t)NDOM * OUTD * 4);
    float* dis   = (float*)alloc((size_t)NDOM * 4);
    float* ab1   = (float*)alloc((size_t)2 * HD * 4);
    float* ab2   = (float*)alloc((size_t)2 * DDIM * 4);
    float* ab_s  = (float*)alloc((size_t)2 * DDIM * 4);
    // zeroed region (single memset)
    char* zbase = w + off;
    int* deg_res  = (int*)alloc((size_t)Nr * 4);
    int* cur_res  = (int*)alloc((size_t)Nr * 4);
    int* deg_sse  = (int*)alloc((size_t)Ns * 4);
    int* cur_sse  = (int*)alloc((size_t)Ns * 4);
    float* cnt    = (float*)alloc((size_t)Ns * 4);
    float* pooled = (float*)alloc((size_t)Ns * DDIM * 4);
    float* bsum1  = (float*)alloc((size_t)2 * HD * 4);
    float* bsum2  = (float*)alloc((size_t)2 * DDIM * 4);
    float* bsum_s = (float*)alloc((size_t)2 * DDIM * 4);
    float* sse_g  = (float*)alloc((size_t)DDIM * 4);   // zeroed: col_sum_atomic target
    size_t zbytes = (size_t)((w + off) - zbase);
    // f16 split buffers
    f16* A1hi  = (f16*)alloc((size_t)Nr * KP1 * 2);
    f16* A1lo  = (f16*)alloc((size_t)Nr * KP1 * 2);
    f16* W1thi = (f16*)alloc((size_t)HD * KP1 * 2);
    f16* W1tlo = (f16*)alloc((size_t)HD * KP1 * 2);
    f16* W2thi = (f16*)alloc((size_t)HD * HD * 2);
    f16* W2tlo = (f16*)alloc((size_t)HD * HD * 2);
    // A2 aliases A1's region (disjoint lifetimes)
    f16* A2hi = A1hi;
    f16* A2lo = A1hi + (size_t)Nr * HD;
    bool use_mfma = (need <= ws_size);
    (void)n_in; (void)out_size;

    hipMemsetAsync(zbase, 0, zbytes, stream);

    const int* src_res = ei_res;
    const int* dst_res = ei_res + E_res;
    const int* src_sse = ei_sse;
    const int* dst_sse = ei_sse + E_sse;
    const int* src_dom = ei_dom;
    const int* dst_dom = ei_dom + E_dom;

    // CSR builds
    count_deg<<<(E_res + 255) / 256, 256, 0, stream>>>(dst_res, E_res, deg_res);
    exclusive_scan<<<1, 256, 0, stream>>>(deg_res, rp_res, Nr);
    csr_fill<<<(E_res + 255) / 256, 256, 0, stream>>>(src_res, dst_res, E_res, rp_res, cur_res, col_res);
    count_deg<<<(E_sse + 255) / 256, 256, 0, stream>>>(dst_sse, E_sse, deg_sse);
    exclusive_scan<<<1, 256, 0, stream>>>(deg_sse, rp_sse, Ns);
    csr_fill<<<(E_sse + 255) / 256, 256, 0, stream>>>(src_sse, dst_sse, E_sse, rp_sse, cur_sse, col_sse);

    int mrows = (Nr + 127) / 128;

    // ---- Level 1, GAT1 (concat) ----
    if (use_mfma) {
        split_rows<<<2048, 256, 0, stream>>>(x_res, A1hi, A1lo, Nr, FIN, KP1);
        split_w_t<<<512, 256, 0, stream>>>(W1, W1thi, W1tlo, FIN, HD, KP1);
        split_w_t<<<512, 256, 0, stream>>>(W2, W2thi, W2tlo, HD, HD, HD);
        mfma_gemm<<<dim3(HD / 64, mrows), 256, 0, stream>>>(A1hi, A1lo, W1thi, W1tlo, A, Nr, HD, KP1);
    } else {
        sgemm64<<<dim3(HD / 64, (Nr + 63) / 64), 256, 0, stream>>>(x_res, W1, A, Nr, HD, FIN);
    }
    att_scores<<<(Nr + 3) / 4, 256, 0, stream>>>(A, asrc1, adst1, es, ed, Nr);
    gat_aggregate<<<Nr, 256, 0, stream>>>(A, es, ed, rp_res, col_res, b1, Bb, Nr, 1);
    bn_stats<<<512, 256, 0, stream>>>(Bb, bsum1, (long)Nr * HD, HD);
    bn_finalize<<<2, 256, 0, stream>>>(bsum1, g1, be1, ab1, 1.f / Nr, HD);

    // ---- Level 1, GAT2 (mean heads) ----
    if (use_mfma) {
        bn_apply_split<<<2048, 256, 0, stream>>>(Bb, ab1, A2hi, A2lo, (long)Nr * HD, HD);
        mfma_gemm<<<dim3(HD / 64, mrows), 256, 0, stream>>>(A2hi, A2lo, W2thi, W2tlo, A, Nr, HD, HD);
    } else {
        bn_apply_relu<<<2048, 256, 0, stream>>>(Bb, ab1, Bb, (long)Nr * HD, HD);
        sgemm64<<<dim3(HD / 64, (Nr + 63) / 64), 256, 0, stream>>>(Bb, W2, A, Nr, HD, HD);
    }
    att_scores<<<(Nr + 3) / 4, 256, 0, stream>>>(A, asrc2, adst2, es, ed, Nr);
    gat_aggregate<<<Nr, 256, 0, stream>>>(A, es, ed, rp_res, col_res, b2, C2, Nr, 0);
    bn_stats<<<512, 256, 0, stream>>>(C2, bsum2, (long)Nr * DDIM, DDIM);
    bn_finalize<<<1, 128, 0, stream>>>(bsum2, g2, be2, ab2, 1.f / Nr, DDIM);
    bn_apply_relu<<<2048, 256, 0, stream>>>(C2, ab2, C2, (long)Nr * DDIM, DDIM);

    // ---- pool residues -> SSE ----
    count_res<<<(Nr + 255) / 256, 256, 0, stream>>>(res_sse_id, cnt, Nr);
    pool_res<<<2048, 256, 0, stream>>>(C2, res_sse_id, pooled, Nr);
    build_xsse<<<(Ns * SSEIN + 255) / 256, 256, 0, stream>>>(pooled, cnt, sse_ss, xsse, Ns);

    // ---- Level 2: SSE GAT ----
    sgemm64<<<dim3(HD / 64, (Ns + 63) / 64), 256, 0, stream>>>(xsse, Ws, h_s, Ns, HD, SSEIN);
    att_scores<<<(Ns + 3) / 4, 256, 0, stream>>>(h_s, asrcs, adsts, es, ed, Ns);
    gat_aggregate<<<Ns, 256, 0, stream>>>(h_s, es, ed, rp_sse, col_sse, bs, xs_o, Ns, 0);
    bn_stats<<<512, 256, 0, stream>>>(xs_o, bsum_s, (long)Ns * DDIM, DDIM);
    bn_finalize<<<1, 128, 0, stream>>>(bsum_s, gs, bes, ab_s, 1.f / Ns, DDIM);
    bn_apply_relu<<<512, 256, 0, stream>>>(xs_o, ab_s, xs_o, (long)Ns * DDIM, DDIM);

    // ---- pool SSE -> domains; GCN; BN ----
    pool_dom<<<NDOM, DDIM, 0, stream>>>(xs_o, xdom);
    sgemm64<<<dim3(OUTD / 64, 1), 256, 0, stream>>>(xdom, Wd, hdom, NDOM, OUTD, DDIM);
    gcn_prep<<<1, 256, 0, stream>>>(src_dom, dst_dom, E_dom, dis);
    gcn_agg<<<NDOM, OUTD, 0, stream>>>(hdom, src_dom, dst_dom, E_dom, dis, bd, gdom);
    bn_small_relu<<<1, OUTD, 0, stream>>>(gdom, gd, bed, gdom2, NDOM, OUTD);

    // ---- readout ----
    col_sum_atomic<<<128, 256, 0, stream>>>(xs_o, sse_g, (long)Ns * DDIM, DDIM);
    readout<<<1, OUTD, 0, stream>>>(sse_g, 1.f / (float)Ns, gdom2, Wproj, bproj, Wread, bread, (float*)d_out);
}

// Round 5
// 952.997 us; speedup vs baseline: 2.0923x; 1.0916x over previous
//
#include <hip/hip_runtime.h>
#include <math.h>

// ---------------- problem constants (match reference) ----------------
#define NRES   20000
#define NSSE   2000
#define NDOM   40
#define FIN    1302
#define NHEAD  4
#define DDIM   128
#define HD     512      // NHEAD*DDIM
#define OUTD   256
#define SSEIN  132      // DDIM+3+1
#define BN_EPS 1e-5f
#define KP1    1312     // FIN padded to multiple of 32

typedef _Float16 f16;
typedef __attribute__((ext_vector_type(8))) _Float16 f16x8;
typedef __attribute__((ext_vector_type(4))) float f32x4;

__device__ __forceinline__ float leaky(float v) { return v > 0.f ? v : 0.2f * v; }

// ---------------- f32 -> (hi,lo) f16 split, row layout [M][Kpad], zero-padded ----------
__global__ __launch_bounds__(256) void split_rows(const float* __restrict__ X,
                                                  f16* __restrict__ hi, f16* __restrict__ lo,
                                                  int M, int K, int Kpad) {
    long slots = (long)M * (Kpad >> 3);
    long stride = (long)gridDim.x * blockDim.x;
    for (long s = (long)blockIdx.x * blockDim.x + threadIdx.x; s < slots; s += stride) {
        int m = (int)(s / (Kpad >> 3));
        int kc = (int)(s % (Kpad >> 3)) << 3;
        f16x8 h, l;
#pragma unroll
        for (int j = 0; j < 8; ++j) {
            int k = kc + j;
            float v = (k < K) ? X[(long)m * K + k] : 0.f;
            f16 hh = (f16)v;
            h[j] = hh;
            l[j] = (f16)(v - (float)hh);
        }
        long o = ((long)m * Kpad + kc);
        *(f16x8*)&hi[o] = h;
        *(f16x8*)&lo[o] = l;
    }
}

// ---------------- W[K][N] f32 -> transposed split [N][Kpad] --------------------------
__global__ __launch_bounds__(256) void split_w_t(const float* __restrict__ W,
                                                 f16* __restrict__ hi, f16* __restrict__ lo,
                                                 int K, int N, int Kpad) {
    long total = (long)N * Kpad;
    long stride = (long)gridDim.x * blockDim.x;
    for (long i = (long)blockIdx.x * blockDim.x + threadIdx.x; i < total; i += stride) {
        int n = (int)(i / Kpad), k = (int)(i % Kpad);
        float v = (k < K) ? W[(long)k * N + n] : 0.f;
        f16 h = (f16)v;
        hi[i] = h;
        lo[i] = (f16)(v - (float)h);
    }
}

// ---------------- BN apply + ReLU fused with hi/lo split (for GEMM2 input) -----------
__global__ __launch_bounds__(256) void bn_apply_split(const float* __restrict__ x,
                                                      const float* __restrict__ ab,
                                                      f16* __restrict__ hi, f16* __restrict__ lo,
                                                      long total, int C) {
    long stride = (long)gridDim.x * blockDim.x;
    for (long i = (long)blockIdx.x * blockDim.x + threadIdx.x; i < total; i += stride) {
        int c = (int)(i % C);
        float v = fmaxf(0.f, x[i] * ab[c] + ab[C + c]);
        f16 h = (f16)v;
        hi[i] = h;
        lo[i] = (f16)(v - (float)h);
    }
}

// ---------------- MFMA GEMM: C[M][N] = A @ B via f16 hi/lo 3-pass --------------------
// N fixed at 512 (8 col-blocks of 64). 1D grid with XCD-aware swizzle: all 8 col-blocks
// of a row panel get bid%8 == panel%8 -> same XCD L2 -> A panel fetched once, not 8x.
__global__ __launch_bounds__(256) void mfma_gemm(const f16* __restrict__ Ahi,
                                                 const f16* __restrict__ Alo,
                                                 const f16* __restrict__ Bthi,
                                                 const f16* __restrict__ Btlo,
                                                 float* __restrict__ C,
                                                 int M, int RB, int Kpad) {
    // decode swizzled block id: xcd = bid&7 selects row-panel group member
    int bid = blockIdx.x;
    int xcd = bid & 7;
    int rem = bid >> 3;
    int x = rem & 7;            // col block 0..7 (N = 512)
    int y = (rem >> 3) * 8 + xcd;  // row panel
    if (y >= RB) return;

    __shared__ f16 As[2][128][40];  // [hi/lo][row][k]  pitch 40 (80B)
    __shared__ f16 Bs[2][64][40];   // [hi/lo][col][k]
    int t = threadIdx.x;
    int w = t >> 6, l = t & 63;
    int wr = w >> 1, wc = w & 1;
    int row0 = y * 128, col0 = x * 64;

    f32x4 acc[4][2] = {};

    for (int k0 = 0; k0 < Kpad; k0 += 32) {
#pragma unroll
        for (int r = 0; r < 2; ++r) {
            int s = t + (r << 8);
            int row = s >> 2, kc = (s & 3) << 3;
            int grow = row0 + row; if (grow >= M) grow = M - 1;  // safe read; result discarded
            long gi = (long)grow * Kpad + k0 + kc;
            *(f16x8*)&As[0][row][kc] = *(const f16x8*)&Ahi[gi];
            *(f16x8*)&As[1][row][kc] = *(const f16x8*)&Alo[gi];
        }
        {
            int col = t >> 2, kc = (t & 3) << 3;
            long gi = (long)(col0 + col) * Kpad + k0 + kc;
            *(f16x8*)&Bs[0][col][kc] = *(const f16x8*)&Bthi[gi];
            *(f16x8*)&Bs[1][col][kc] = *(const f16x8*)&Btlo[gi];
        }
        __syncthreads();

        int lr = l & 15, ks = (l >> 4) << 3;
        f16x8 ah[4], al[4], bh[2], bl[2];
#pragma unroll
        for (int fi = 0; fi < 4; ++fi) {
            int row = wr * 64 + fi * 16 + lr;
            ah[fi] = *(const f16x8*)&As[0][row][ks];
            al[fi] = *(const f16x8*)&As[1][row][ks];
        }
#pragma unroll
        for (int fj = 0; fj < 2; ++fj) {
            int col = wc * 32 + fj * 16 + lr;
            bh[fj] = *(const f16x8*)&Bs[0][col][ks];
            bl[fj] = *(const f16x8*)&Bs[1][col][ks];
        }
#pragma unroll
        for (int fi = 0; fi < 4; ++fi)
#pragma unroll
            for (int fj = 0; fj < 2; ++fj) {
                acc[fi][fj] = __builtin_amdgcn_mfma_f32_16x16x32_f16(ah[fi], bh[fj], acc[fi][fj], 0, 0, 0);
                acc[fi][fj] = __builtin_amdgcn_mfma_f32_16x16x32_f16(ah[fi], bl[fj], acc[fi][fj], 0, 0, 0);
                acc[fi][fj] = __builtin_amdgcn_mfma_f32_16x16x32_f16(al[fi], bh[fj], acc[fi][fj], 0, 0, 0);
            }
        __syncthreads();
    }
    // epilogue: C/D layout (m89-verified): col = lane&15, row = (lane>>4)*4 + reg
    int lr = l & 15, lq = l >> 4;
#pragma unroll
    for (int fi = 0; fi < 4; ++fi)
#pragma unroll
        for (int fj = 0; fj < 2; ++fj)
#pragma unroll
            for (int r = 0; r < 4; ++r) {
                int row = row0 + wr * 64 + fi * 16 + lq * 4 + r;
                int col = col0 + wc * 32 + fj * 16 + lr;
                if (row < M) C[(long)row * 512 + col] = acc[fi][fj][r];
            }
}

// ---------------- generic tiled f32 GEMM (small GEMMs + fallback) ----------------
__global__ __launch_bounds__(256) void sgemm64(const float* __restrict__ A,
                                               const float* __restrict__ B,
                                               float* __restrict__ C,
                                               int M, int N, int K) {
    __shared__ float As[16][68];
    __shared__ float Bs[16][68];
    int t = threadIdx.x;
    int tx = t & 15, ty = t >> 4;
    int row0 = blockIdx.y * 64, col0 = blockIdx.x * 64;
    float acc[4][4] = {};
    for (int k0 = 0; k0 < K; k0 += 16) {
#pragma unroll
        for (int i = 0; i < 4; ++i) {
            int idx = t * 4 + i;
            int r = idx >> 4, kk = idx & 15;
            int gr = row0 + r, gk = k0 + kk;
            As[kk][r] = (gr < M && gk < K) ? A[(long)gr * K + gk] : 0.f;
        }
#pragma unroll
        for (int i = 0; i < 4; ++i) {
            int idx = t * 4 + i;
            int kk = idx >> 6, c = idx & 63;
            int gk = k0 + kk, gc = col0 + c;
            Bs[kk][c] = (gk < K && gc < N) ? B[(long)gk * N + gc] : 0.f;
        }
        __syncthreads();
#pragma unroll
        for (int kk = 0; kk < 16; ++kk) {
            float a[4], b[4];
#pragma unroll
            for (int i = 0; i < 4; ++i) a[i] = As[kk][ty * 4 + i];
#pragma unroll
            for (int j = 0; j < 4; ++j) b[j] = Bs[kk][tx * 4 + j];
#pragma unroll
            for (int i = 0; i < 4; ++i)
#pragma unroll
                for (int j = 0; j < 4; ++j) acc[i][j] += a[i] * b[j];
        }
        __syncthreads();
    }
#pragma unroll
    for (int i = 0; i < 4; ++i) {
        int r = row0 + ty * 4 + i;
        if (r >= M) continue;
#pragma unroll
        for (int j = 0; j < 4; ++j) {
            int c = col0 + tx * 4 + j;
            if (c < N) C[(long)r * N + c] = acc[i][j];
        }
    }
}

// ---------------- CSR build ----------------
__global__ void count_deg(const int* __restrict__ dst, int E, int* __restrict__ deg) {
    int i = blockIdx.x * blockDim.x + threadIdx.x;
    if (i < E) atomicAdd(&deg[dst[i]], 1);
}

__global__ __launch_bounds__(256) void exclusive_scan(const int* __restrict__ deg,
                                                      int* __restrict__ row_ptr, int N) {
    __shared__ int part[256];
    __shared__ int base[257];
    int t = threadIdx.x;
    int chunk = (N + 255) / 256;
    int lo = t * chunk, hi = min(lo + chunk, N);
    if (lo > N) lo = N;
    if (hi > N) hi = N;
    int s = 0;
    for (int i = lo; i < hi; ++i) s += deg[i];
    part[t] = s;
    __syncthreads();
    if (t == 0) {
        int r = 0;
        for (int i = 0; i < 256; ++i) { base[i] = r; r += part[i]; }
        base[256] = r;
    }
    __syncthreads();
    int run = base[t];
    for (int i = lo; i < hi; ++i) { row_ptr[i] = run; run += deg[i]; }
    if (t == 0) row_ptr[N] = base[256];
}

__global__ void csr_fill(const int* __restrict__ src, const int* __restrict__ dst, int E,
                         const int* __restrict__ row_ptr, int* __restrict__ cursor,
                         int* __restrict__ col) {
    int i = blockIdx.x * blockDim.x + threadIdx.x;
    if (i < E) {
        int d = dst[i];
        int p = row_ptr[d] + atomicAdd(&cursor[d], 1);
        col[p] = src[i];
    }
}

// ---------------- attention scores ----------------
__global__ __launch_bounds__(256) void att_scores(const float* __restrict__ h,
                                                  const float* __restrict__ asrc,
                                                  const float* __restrict__ adst,
                                                  float* __restrict__ es,
                                                  float* __restrict__ ed, int N) {
    int wid = threadIdx.x >> 6, lane = threadIdx.x & 63;
    int n = blockIdx.x * 4 + wid;
    if (n >= N) return;
    const float* hr = h + (long)n * HD;
    float ps[NHEAD], pd[NHEAD];
#pragma unroll
    for (int hh = 0; hh < NHEAD; ++hh) {
        float s = 0.f, d = 0.f;
#pragma unroll
        for (int j = 0; j < 2; ++j) {
            int c = hh * DDIM + lane + j * 64;
            float v = hr[c];
            s += v * asrc[c];
            d += v * adst[c];
        }
        ps[hh] = s; pd[hh] = d;
    }
#pragma unroll
    for (int off = 32; off > 0; off >>= 1) {
#pragma unroll
        for (int hh = 0; hh < NHEAD; ++hh) {
            ps[hh] += __shfl_xor(ps[hh], off);
            pd[hh] += __shfl_xor(pd[hh], off);
        }
    }
    if (lane == 0) {
#pragma unroll
        for (int hh = 0; hh < NHEAD; ++hh) {
            es[n * NHEAD + hh] = ps[hh];
            ed[n * NHEAD + hh] = pd[hh];
        }
    }
}

// ---------------- GAT aggregation ----------------
__global__ __launch_bounds__(256) void gat_aggregate(const float* __restrict__ h,
                                                     const float* __restrict__ es,
                                                     const float* __restrict__ ed,
                                                     const int* __restrict__ row_ptr,
                                                     const int* __restrict__ col,
                                                     const float* __restrict__ bias,
                                                     float* __restrict__ out,
                                                     int N, int concat) {
    int n = blockIdx.x;
    int t = threadIdx.x;
    int lane = t & 63, wid = t >> 6;
    int s0 = row_ptr[n], s1 = row_ptr[n + 1];

    float edv[NHEAD], vself[NHEAD];
#pragma unroll
    for (int hh = 0; hh < NHEAD; ++hh) {
        edv[hh] = ed[n * NHEAD + hh];
        vself[hh] = leaky(es[n * NHEAD + hh] + edv[hh]);
    }
    __shared__ float sred[4][NHEAD];
    __shared__ float m[NHEAD], den[NHEAD];

    float lm[NHEAD] = {-1e30f, -1e30f, -1e30f, -1e30f};
    for (int k = s0 + t; k < s1; k += 256) {
        int sn = col[k];
#pragma unroll
        for (int hh = 0; hh < NHEAD; ++hh)
            lm[hh] = fmaxf(lm[hh], leaky(es[sn * NHEAD + hh] + edv[hh]));
    }
#pragma unroll
    for (int off = 32; off > 0; off >>= 1)
#pragma unroll
        for (int hh = 0; hh < NHEAD; ++hh) lm[hh] = fmaxf(lm[hh], __shfl_xor(lm[hh], off));
    if (lane == 0)
#pragma unroll
        for (int hh = 0; hh < NHEAD; ++hh) sred[wid][hh] = lm[hh];
    __syncthreads();
    if (t < NHEAD) {
        float mm = vself[t];
#pragma unroll
        for (int w = 0; w < 4; ++w) mm = fmaxf(mm, sred[w][t]);
        m[t] = mm;
    }
    __syncthreads();
    float mh[NHEAD];
#pragma unroll
    for (int hh = 0; hh < NHEAD; ++hh) mh[hh] = m[hh];

    float ls[NHEAD] = {0.f, 0.f, 0.f, 0.f};
    for (int k = s0 + t; k < s1; k += 256) {
        int sn = col[k];
#pragma unroll
        for (int hh = 0; hh < NHEAD; ++hh)
            ls[hh] += expf(leaky(es[sn * NHEAD + hh] + edv[hh]) - mh[hh]);
    }
#pragma unroll
    for (int off = 32; off > 0; off >>= 1)
#pragma unroll
        for (int hh = 0; hh < NHEAD; ++hh) ls[hh] += __shfl_xor(ls[hh], off);
    if (lane == 0)
#pragma unroll
        for (int hh = 0; hh < NHEAD; ++hh) sred[wid][hh] = ls[hh];
    __syncthreads();
    if (t < NHEAD)
        den[t] = sred[0][t] + sred[1][t] + sred[2][t] + sred[3][t] + expf(vself[t] - m[t]);
    __syncthreads();
    float inv[NHEAD];
#pragma unroll
    for (int hh = 0; hh < NHEAD; ++hh) inv[hh] = 1.f / (den[hh] + 1e-16f);

    int d0 = t, d1 = t + 256;
    int h0 = t >> 7, h1 = h0 + 2;
    float acc0, acc1;
    {
        float a0 = expf(vself[h0] - mh[h0]) * inv[h0];
        float a1 = expf(vself[h1] - mh[h1]) * inv[h1];
        acc0 = a0 * h[(long)n * HD + d0];
        acc1 = a1 * h[(long)n * HD + d1];
    }
    __shared__ float alph[64 * NHEAD];
    for (int base = s0; base < s1; base += 64) {
        int cnt = min(64, s1 - base);
        if (t < cnt * NHEAD) {
            int e = t >> 2, hh = t & 3;
            int sn = col[base + e];
            float v = leaky(es[sn * NHEAD + hh] + edv[hh]);
            alph[(e << 2) | hh] = expf(v - mh[hh]) * inv[hh];
        }
        __syncthreads();
        for (int e = 0; e < cnt; ++e) {
            int sn = col[base + e];
            const float* hs = h + (long)sn * HD;
            acc0 += alph[(e << 2) | h0] * hs[d0];
            acc1 += alph[(e << 2) | h1] * hs[d1];
        }
        __syncthreads();
    }

    if (concat) {
        out[(long)n * HD + d0] = acc0 + bias[d0];
        out[(long)n * HD + d1] = acc1 + bias[d1];
    } else {
        __shared__ float accs[HD];
        accs[d0] = acc0;
        accs[d1] = acc1;
        __syncthreads();
        if (t < DDIM)
            out[(long)n * DDIM + t] =
                (accs[t] + accs[t + 128] + accs[t + 256] + accs[t + 384]) * 0.25f + bias[t];
    }
}

// ---------------- BatchNorm ----------------
__global__ __launch_bounds__(256) void bn_stats(const float* __restrict__ x,
                                                float* __restrict__ sums, long total, int C) {
    long gid = (long)blockIdx.x * blockDim.x + threadIdx.x;
    long stride = (long)gridDim.x * blockDim.x;  // multiple of C
    int c = (int)(gid % C);
    float s = 0.f, s2 = 0.f;
    for (long i = gid; i < total; i += stride) {
        float v = x[i];
        s += v; s2 += v * v;
    }
    atomicAdd(&sums[c], s);
    atomicAdd(&sums[C + c], s2);
}

__global__ void bn_finalize(const float* __restrict__ sums, const float* __restrict__ g,
                            const float* __restrict__ be, float* __restrict__ ab,
                            float invN, int C) {
    int c = blockIdx.x * blockDim.x + threadIdx.x;
    if (c < C) {
        float mean = sums[c] * invN;
        float var = sums[C + c] * invN - mean * mean;
        float sc = g[c] * rsqrtf(var + BN_EPS);
        ab[c] = sc;
        ab[C + c] = be[c] - mean * sc;
    }
}

__global__ __launch_bounds__(256) void bn_apply_relu(const float* __restrict__ x,
                                                     const float* __restrict__ ab,
                                                     float* __restrict__ y, long total, int C) {
    long gid = (long)blockIdx.x * blockDim.x + threadIdx.x;
    long stride = (long)gridDim.x * blockDim.x;
    for (long i = gid; i < total; i += stride) {
        int c = (int)(i % C);
        y[i] = fmaxf(0.f, x[i] * ab[c] + ab[C + c]);
    }
}

// ---------------- residue -> SSE pooling ----------------
__global__ void count_res(const int* __restrict__ sid, float* __restrict__ cnt, int Nr) {
    int i = blockIdx.x * blockDim.x + threadIdx.x;
    if (i < Nr) atomicAdd(&cnt[sid[i]], 1.f);
}

__global__ __launch_bounds__(256) void pool_res(const float* __restrict__ x,
                                                const int* __restrict__ sid,
                                                float* __restrict__ pooled, int Nr) {
    long total = (long)Nr * DDIM;
    long stride = (long)gridDim.x * blockDim.x;
    for (long i = (long)blockIdx.x * blockDim.x + threadIdx.x; i < total; i += stride) {
        int n = (int)(i / DDIM), c = (int)(i % DDIM);
        atomicAdd(&pooled[(long)sid[n] * DDIM + c], x[i]);
    }
}

__global__ void build_xsse(const float* __restrict__ pooled, const float* __restrict__ cnt,
                           const int* __restrict__ sstype, float* __restrict__ xsse, int Ns) {
    int i = blockIdx.x * blockDim.x + threadIdx.x;
    if (i >= Ns * SSEIN) return;
    int s = i / SSEIN, j = i % SSEIN;
    float c = cnt[s];
    float v;
    if (j < DDIM) v = pooled[(long)s * DDIM + j] / fmaxf(c, 1.f);
    else if (j < DDIM + 3) v = (sstype[s] == (j - DDIM)) ? 1.f : 0.f;
    else v = c / (float)NRES;
    xsse[i] = v;
}

// ---------------- SSE -> domain pooling ----------------
__global__ void pool_dom(const float* __restrict__ x, float* __restrict__ xdom) {
    int d = blockIdx.x, c = threadIdx.x;
    int spd = NSSE / NDOM;
    int r0 = d * spd;
    int r1 = (d == NDOM - 1) ? NSSE : r0 + spd;
    float acc = 0.f;
    for (int r = r0; r < r1; ++r) acc += x[(long)r * DDIM + c];
    xdom[d * DDIM + c] = acc / (float)(r1 - r0);
}

// ---------------- domain GCN ----------------
__global__ __launch_bounds__(256) void gcn_prep(const int* __restrict__ src,
                                                const int* __restrict__ dst, int E,
                                                float* __restrict__ dis) {
    __shared__ float degL[NDOM];
    int t = threadIdx.x;
    if (t < NDOM) degL[t] = 1.f;
    __syncthreads();
    for (int e = t; e < E; e += blockDim.x) atomicAdd(&degL[dst[e]], 1.f);
    __syncthreads();
    if (t < NDOM) dis[t] = rsqrtf(fmaxf(degL[t], 1e-12f));
}

__global__ void gcn_agg(const float* __restrict__ hdom, const int* __restrict__ src,
                        const int* __restrict__ dst, int E, const float* __restrict__ dis,
                        const float* __restrict__ bd, float* __restrict__ outd) {
    int n = blockIdx.x, c = threadIdx.x;
    float dn = dis[n];
    float acc = dn * dn * hdom[n * OUTD + c];
    for (int e = 0; e < E; ++e)
        if (dst[e] == n) acc += dis[src[e]] * dn * hdom[src[e] * OUTD + c];
    outd[n * OUTD + c] = acc + bd[c];
}

__global__ void bn_small_relu(const float* __restrict__ x, const float* __restrict__ g,
                              const float* __restrict__ be, float* __restrict__ y,
                              int N, int C) {
    int c = threadIdx.x;
    if (c >= C) return;
    float s = 0.f, s2 = 0.f;
#pragma unroll 8
    for (int r = 0; r < N; ++r) {
        float v = x[r * C + c];
        s += v; s2 += v * v;
    }
    float mean = s / N;
    float var = s2 / N - mean * mean;
    float sc = g[c] * rsqrtf(var + BN_EPS);
    float sh = be[c] - mean * sc;
#pragma unroll 8
    for (int r = 0; r < N; ++r) y[r * C + c] = fmaxf(0.f, x[r * C + c] * sc + sh);
}

// ---------------- parallel column sum ----------------
__global__ __launch_bounds__(256) void col_sum_atomic(const float* __restrict__ x,
                                                      float* __restrict__ out,
                                                      long total, int C) {
    long gid = (long)blockIdx.x * blockDim.x + threadIdx.x;
    long stride = (long)gridDim.x * blockDim.x;  // multiple of C
    int c = (int)(gid % C);
    float s = 0.f;
    for (long i = gid; i < total; i += stride) s += x[i];
    atomicAdd(&out[c], s);
}

// ---------------- readout ----------------
__global__ __launch_bounds__(256) void readout(const float* __restrict__ sse_sum,
                                               float invNs,
                                               const float* __restrict__ xdom_bn,
                                               const float* __restrict__ Wproj,
                                               const float* __restrict__ bproj,
                                               const float* __restrict__ Wread,
                                               const float* __restrict__ bread,
                                               float* __restrict__ out) {
    int c = threadIdx.x;
    __shared__ float v[2 * OUTD];
    float s = 0.f;
#pragma unroll 8
    for (int k = 0; k < DDIM; ++k) s += sse_sum[k] * Wproj[k * OUTD + c];
    v[c] = s * invNs + bproj[c];
    float dm = 0.f;
#pragma unroll 8
    for (int r = 0; r < NDOM; ++r) dm += xdom_bn[r * OUTD + c];
    v[OUTD + c] = dm / (float)NDOM;
    __syncthreads();
    float o = bread[c];
#pragma unroll 8
    for (int k = 0; k < 2 * OUTD; ++k) o += v[k] * Wread[k * OUTD + c];
    __shared__ float sq[256];
    sq[c] = o * o;
    __syncthreads();
    for (int off = 128; off > 0; off >>= 1) {
        if (c < off) sq[c] += sq[c + off];
        __syncthreads();
    }
    float scale = 1.f / fmaxf(sqrtf(sq[0]), 1e-12f);
    out[c] = o * scale;
}

// ---------------- launcher ----------------
extern "C" void kernel_launch(void* const* d_in, const int* in_sizes, int n_in,
                              void* d_out, int out_size, void* d_ws, size_t ws_size,
                              hipStream_t stream) {
    const float* x_res = (const float*)d_in[0];
    const int* ei_res = (const int*)d_in[1];
    const int* ei_sse = (const int*)d_in[2];
    const int* ei_dom = (const int*)d_in[3];
    const int* res_sse_id = (const int*)d_in[4];
    const int* sse_ss = (const int*)d_in[5];
    const int E_res = in_sizes[1] / 2;
    const int E_sse = in_sizes[2] / 2;
    const int E_dom = in_sizes[3] / 2;
    const int Nr = in_sizes[4];
    const int Ns = in_sizes[5];
    const float* W1 = (const float*)d_in[7];
    const float* asrc1 = (const float*)d_in[8];
    const float* adst1 = (const float*)d_in[9];
    const float* b1 = (const float*)d_in[10];
    const float* g1 = (const float*)d_in[11];
    const float* be1 = (const float*)d_in[12];
    const float* W2 = (const float*)d_in[13];
    const float* asrc2 = (const float*)d_in[14];
    const float* adst2 = (const float*)d_in[15];
    const float* b2 = (const float*)d_in[16];
    const float* g2 = (const float*)d_in[17];
    const float* be2 = (const float*)d_in[18];
    const float* Ws = (const float*)d_in[19];
    const float* asrcs = (const float*)d_in[20];
    const float* adsts = (const float*)d_in[21];
    const float* bs = (const float*)d_in[22];
    const float* gs = (const float*)d_in[23];
    const float* bes = (const float*)d_in[24];
    const float* Wd = (const float*)d_in[25];
    const float* bd = (const float*)d_in[26];
    const float* gd = (const float*)d_in[27];
    const float* bed = (const float*)d_in[28];
    const float* Wproj = (const float*)d_in[29];
    const float* bproj = (const float*)d_in[30];
    const float* Wread = (const float*)d_in[31];
    const float* bread = (const float*)d_in[32];

    // ---- workspace layout: clamp pointers, track unclamped need for fallback decision ----
    char* w = (char*)d_ws;
    size_t off = 0, need = 0;
    auto alloc = [&](size_t bytes) -> char* {
        char* p = w + off;
        size_t inc = (bytes + 255) & ~(size_t)255;
        need += inc;
        if (off + inc > ws_size) inc = (off < ws_size) ? (ws_size - off) : 0;
        off += inc;
        return p;
    };
    float* A     = (float*)alloc((size_t)Nr * HD * 4);   // h1 / h2
    float* Bb    = (float*)alloc((size_t)Nr * HD * 4);   // gat1 out (pre-BN)
    float* C2    = (float*)alloc((size_t)Nr * DDIM * 4);
    float* es    = (float*)alloc((size_t)Nr * NHEAD * 4);
    float* ed    = (float*)alloc((size_t)Nr * NHEAD * 4);
    int* rp_res  = (int*)alloc((size_t)(Nr + 1) * 4);
    int* col_res = (int*)alloc((size_t)E_res * 4);
    int* rp_sse  = (int*)alloc((size_t)(Ns + 1) * 4);
    int* col_sse = (int*)alloc((size_t)E_sse * 4);
    float* xsse  = (float*)alloc((size_t)Ns * SSEIN * 4);
    float* h_s   = (float*)alloc((size_t)Ns * HD * 4);
    float* xs_o  = (float*)alloc((size_t)Ns * DDIM * 4);
    float* xdom  = (float*)alloc((size_t)NDOM * DDIM * 4);
    float* hdom  = (float*)alloc((size_t)NDOM * OUTD * 4);
    float* gdom  = (float*)alloc((size_t)NDOM * OUTD * 4);
    float* gdom2 = (float*)alloc((size_t)NDOM * OUTD * 4);
    float* dis   = (float*)alloc((size_t)NDOM * 4);
    float* ab1   = (float*)alloc((size_t)2 * HD * 4);
    float* ab2   = (float*)alloc((size_t)2 * DDIM * 4);
    float* ab_s  = (float*)alloc((size_t)2 * DDIM * 4);
    // zeroed region (single memset)
    char* zbase = w + off;
    int* deg_res  = (int*)alloc((size_t)Nr * 4);
    int* cur_res  = (int*)alloc((size_t)Nr * 4);
    int* deg_sse  = (int*)alloc((size_t)Ns * 4);
    int* cur_sse  = (int*)alloc((size_t)Ns * 4);
    float* cnt    = (float*)alloc((size_t)Ns * 4);
    float* pooled = (float*)alloc((size_t)Ns * DDIM * 4);
    float* bsum1  = (float*)alloc((size_t)2 * HD * 4);
    float* bsum2  = (float*)alloc((size_t)2 * DDIM * 4);
    float* bsum_s = (float*)alloc((size_t)2 * DDIM * 4);
    float* sse_g  = (float*)alloc((size_t)DDIM * 4);   // zeroed: col_sum_atomic target
    size_t zbytes = (size_t)((w + off) - zbase);
    // f16 split buffers
    f16* A1hi  = (f16*)alloc((size_t)Nr * KP1 * 2);
    f16* A1lo  = (f16*)alloc((size_t)Nr * KP1 * 2);
    f16* W1thi = (f16*)alloc((size_t)HD * KP1 * 2);
    f16* W1tlo = (f16*)alloc((size_t)HD * KP1 * 2);
    f16* W2thi = (f16*)alloc((size_t)HD * HD * 2);
    f16* W2tlo = (f16*)alloc((size_t)HD * HD * 2);
    // A2 aliases A1's region (disjoint lifetimes)
    f16* A2hi = A1hi;
    f16* A2lo = A1hi + (size_t)Nr * HD;
    bool use_mfma = (need <= ws_size);
    (void)n_in; (void)out_size;

    hipMemsetAsync(zbase, 0, zbytes, stream);

    const int* src_res = ei_res;
    const int* dst_res = ei_res + E_res;
    const int* src_sse = ei_sse;
    const int* dst_sse = ei_sse + E_sse;
    const int* src_dom = ei_dom;
    const int* dst_dom = ei_dom + E_dom;

    // CSR builds
    count_deg<<<(E_res + 255) / 256, 256, 0, stream>>>(dst_res, E_res, deg_res);
    exclusive_scan<<<1, 256, 0, stream>>>(deg_res, rp_res, Nr);
    csr_fill<<<(E_res + 255) / 256, 256, 0, stream>>>(src_res, dst_res, E_res, rp_res, cur_res, col_res);
    count_deg<<<(E_sse + 255) / 256, 256, 0, stream>>>(dst_sse, E_sse, deg_sse);
    exclusive_scan<<<1, 256, 0, stream>>>(deg_sse, rp_sse, Ns);
    csr_fill<<<(E_sse + 255) / 256, 256, 0, stream>>>(src_sse, dst_sse, E_sse, rp_sse, cur_sse, col_sse);

    int RB = (Nr + 127) / 128;                 // row panels
    int gemm_blocks = 64 * ((RB + 7) / 8);     // 8 cols x padded rows (swizzled 1D)

    // ---- Level 1, GAT1 (concat) ----
    if (use_mfma) {
        split_rows<<<2048, 256, 0, stream>>>(x_res, A1hi, A1lo, Nr, FIN, KP1);
        split_w_t<<<512, 256, 0, stream>>>(W1, W1thi, W1tlo, FIN, HD, KP1);
        split_w_t<<<512, 256, 0, stream>>>(W2, W2thi, W2tlo, HD, HD, HD);
        mfma_gemm<<<gemm_blocks, 256, 0, stream>>>(A1hi, A1lo, W1thi, W1tlo, A, Nr, RB, KP1);
    } else {
        sgemm64<<<dim3(HD / 64, (Nr + 63) / 64), 256, 0, stream>>>(x_res, W1, A, Nr, HD, FIN);
    }
    att_scores<<<(Nr + 3) / 4, 256, 0, stream>>>(A, asrc1, adst1, es, ed, Nr);
    gat_aggregate<<<Nr, 256, 0, stream>>>(A, es, ed, rp_res, col_res, b1, Bb, Nr, 1);
    bn_stats<<<512, 256, 0, stream>>>(Bb, bsum1, (long)Nr * HD, HD);
    bn_finalize<<<2, 256, 0, stream>>>(bsum1, g1, be1, ab1, 1.f / Nr, HD);

    // ---- Level 1, GAT2 (mean heads) ----
    if (use_mfma) {
        bn_apply_split<<<2048, 256, 0, stream>>>(Bb, ab1, A2hi, A2lo, (long)Nr * HD, HD);
        mfma_gemm<<<gemm_blocks, 256, 0, stream>>>(A2hi, A2lo, W2thi, W2tlo, A, Nr, RB, HD);
    } else {
        bn_apply_relu<<<2048, 256, 0, stream>>>(Bb, ab1, Bb, (long)Nr * HD, HD);
        sgemm64<<<dim3(HD / 64, (Nr + 63) / 64), 256, 0, stream>>>(Bb, W2, A, Nr, HD, HD);
    }
    att_scores<<<(Nr + 3) / 4, 256, 0, stream>>>(A, asrc2, adst2, es, ed, Nr);
    gat_aggregate<<<Nr, 256, 0, stream>>>(A, es, ed, rp_res, col_res, b2, C2, Nr, 0);
    bn_stats<<<512, 256, 0, stream>>>(C2, bsum2, (long)Nr * DDIM, DDIM);
    bn_finalize<<<1, 128, 0, stream>>>(bsum2, g2, be2, ab2, 1.f / Nr, DDIM);
    bn_apply_relu<<<2048, 256, 0, stream>>>(C2, ab2, C2, (long)Nr * DDIM, DDIM);

    // ---- pool residues -> SSE ----
    count_res<<<(Nr + 255) / 256, 256, 0, stream>>>(res_sse_id, cnt, Nr);
    pool_res<<<2048, 256, 0, stream>>>(C2, res_sse_id, pooled, Nr);
    build_xsse<<<(Ns * SSEIN + 255) / 256, 256, 0, stream>>>(pooled, cnt, sse_ss, xsse, Ns);

    // ---- Level 2: SSE GAT ----
    sgemm64<<<dim3(HD / 64, (Ns + 63) / 64), 256, 0, stream>>>(xsse, Ws, h_s, Ns, HD, SSEIN);
    att_scores<<<(Ns + 3) / 4, 256, 0, stream>>>(h_s, asrcs, adsts, es, ed, Ns);
    gat_aggregate<<<Ns, 256, 0, stream>>>(h_s, es, ed, rp_sse, col_sse, bs, xs_o, Ns, 0);
    bn_stats<<<512, 256, 0, stream>>>(xs_o, bsum_s, (long)Ns * DDIM, DDIM);
    bn_finalize<<<1, 128, 0, stream>>>(bsum_s, gs, bes, ab_s, 1.f / Ns, DDIM);
    bn_apply_relu<<<512, 256, 0, stream>>>(xs_o, ab_s, xs_o, (long)Ns * DDIM, DDIM);

    // ---- pool SSE -> domains; GCN; BN ----
    pool_dom<<<NDOM, DDIM, 0, stream>>>(xs_o, xdom);
    sgemm64<<<dim3(OUTD / 64, 1), 256, 0, stream>>>(xdom, Wd, hdom, NDOM, OUTD, DDIM);
    gcn_prep<<<1, 256, 0, stream>>>(src_dom, dst_dom, E_dom, dis);
    gcn_agg<<<NDOM, OUTD, 0, stream>>>(hdom, src_dom, dst_dom, E_dom, dis, bd, gdom);
    bn_small_relu<<<1, OUTD, 0, stream>>>(gdom, gd, bed, gdom2, NDOM, OUTD);

    // ---- readout ----
    col_sum_atomic<<<128, 256, 0, stream>>>(xs_o, sse_g, (long)Ns * DDIM, DDIM);
    readout<<<1, OUTD, 0, stream>>>(sse_g, 1.f / (float)Ns, gdom2, Wproj, bproj, Wread, bread, (float*)d_out);
}

// Round 6
// 933.480 us; speedup vs baseline: 2.1360x; 1.0209x over previous
//
#include <hip/hip_runtime.h>
#include <math.h>

// ---------------- problem constants (match reference) ----------------
#define NRES   20000
#define NSSE   2000
#define NDOM   40
#define FIN    1302
#define NHEAD  4
#define DDIM   128
#define HD     512      // NHEAD*DDIM
#define OUTD   256
#define SSEIN  132      // DDIM+3+1
#define BN_EPS 1e-5f
#define KP1    1312     // FIN padded to multiple of 32

typedef _Float16 f16;
typedef __attribute__((ext_vector_type(8))) _Float16 f16x8;
typedef __attribute__((ext_vector_type(4))) float f32x4;

__device__ __forceinline__ float leaky(float v) { return v > 0.f ? v : 0.2f * v; }

// ---------------- f32 -> (hi,lo) f16 split, row layout [M][Kpad], zero-padded ----------
__global__ __launch_bounds__(256) void split_rows(const float* __restrict__ X,
                                                  f16* __restrict__ hi, f16* __restrict__ lo,
                                                  int M, int K, int Kpad) {
    long slots = (long)M * (Kpad >> 3);
    long stride = (long)gridDim.x * blockDim.x;
    for (long s = (long)blockIdx.x * blockDim.x + threadIdx.x; s < slots; s += stride) {
        int m = (int)(s / (Kpad >> 3));
        int kc = (int)(s % (Kpad >> 3)) << 3;
        f16x8 h, l;
#pragma unroll
        for (int j = 0; j < 8; ++j) {
            int k = kc + j;
            float v = (k < K) ? X[(long)m * K + k] : 0.f;
            f16 hh = (f16)v;
            h[j] = hh;
            l[j] = (f16)(v - (float)hh);
        }
        long o = ((long)m * Kpad + kc);
        *(f16x8*)&hi[o] = h;
        *(f16x8*)&lo[o] = l;
    }
}

// ---------------- W[K][N] f32 -> transposed split [N][Kpad] --------------------------
__global__ __launch_bounds__(256) void split_w_t(const float* __restrict__ W,
                                                 f16* __restrict__ hi, f16* __restrict__ lo,
                                                 int K, int N, int Kpad) {
    long total = (long)N * Kpad;
    long stride = (long)gridDim.x * blockDim.x;
    for (long i = (long)blockIdx.x * blockDim.x + threadIdx.x; i < total; i += stride) {
        int n = (int)(i / Kpad), k = (int)(i % Kpad);
        float v = (k < K) ? W[(long)k * N + n] : 0.f;
        f16 h = (f16)v;
        hi[i] = h;
        lo[i] = (f16)(v - (float)h);
    }
}

// ---------------- BN apply + ReLU fused with hi/lo split (for GEMM2 input) -----------
__global__ __launch_bounds__(256) void bn_apply_split(const float* __restrict__ x,
                                                      const float* __restrict__ ab,
                                                      f16* __restrict__ hi, f16* __restrict__ lo,
                                                      long total, int C) {
    long stride = (long)gridDim.x * blockDim.x;
    for (long i = (long)blockIdx.x * blockDim.x + threadIdx.x; i < total; i += stride) {
        int c = (int)(i % C);
        float v = fmaxf(0.f, x[i] * ab[c] + ab[C + c]);
        f16 h = (f16)v;
        hi[i] = h;
        lo[i] = (f16)(v - (float)h);
    }
}

// ---------------- MFMA GEMM: C[M][512] = A @ B via f16 hi/lo 3-pass ------------------
// tile 128x128, BK=32, 4 waves (2x2), each wave 64x64 via 4x4 16x16 frags.
// XCD swizzle: panel y -> XCD y&7; its 4 col-blocks spaced 8 apart in bid.
__global__ __launch_bounds__(256) void mfma_gemm(const f16* __restrict__ Ahi,
                                                 const f16* __restrict__ Alo,
                                                 const f16* __restrict__ Bthi,
                                                 const f16* __restrict__ Btlo,
                                                 float* __restrict__ C,
                                                 int M, int RB, int Kpad) {
    int bid = blockIdx.x;
    int xcd = bid & 7;
    int q = bid >> 3;
    int x = q & 3;                  // col block 0..3 (128 wide, N=512)
    int y = (q >> 2) * 8 + xcd;     // row panel
    if (y >= RB) return;

    __shared__ f16 As[2][128][40];  // [hi/lo][row][k] pitch 40
    __shared__ f16 Bs[2][128][40];  // [hi/lo][col][k]
    int t = threadIdx.x;
    int w = t >> 6, l = t & 63;
    int wr = w >> 1, wc = w & 1;
    int row0 = y * 128, col0 = x * 128;

    f32x4 acc[4][4] = {};

    for (int k0 = 0; k0 < Kpad; k0 += 32) {
        // stage A and B tiles: 512 slots each of 8 f16; thread handles slots t, t+256
#pragma unroll
        for (int r = 0; r < 2; ++r) {
            int s = t + (r << 8);
            int row = s >> 2, kc = (s & 3) << 3;
            int grow = row0 + row; if (grow >= M) grow = M - 1;  // safe read; result discarded
            long gia = (long)grow * Kpad + k0 + kc;
            *(f16x8*)&As[0][row][kc] = *(const f16x8*)&Ahi[gia];
            *(f16x8*)&As[1][row][kc] = *(const f16x8*)&Alo[gia];
            long gib = (long)(col0 + row) * Kpad + k0 + kc;
            *(f16x8*)&Bs[0][row][kc] = *(const f16x8*)&Bthi[gib];
            *(f16x8*)&Bs[1][row][kc] = *(const f16x8*)&Btlo[gib];
        }
        __syncthreads();

        int lr = l & 15, ks = (l >> 4) << 3;
        f16x8 ah[4], al[4], bh[4], bl[4];
#pragma unroll
        for (int fi = 0; fi < 4; ++fi) {
            int row = wr * 64 + fi * 16 + lr;
            ah[fi] = *(const f16x8*)&As[0][row][ks];
            al[fi] = *(const f16x8*)&As[1][row][ks];
        }
#pragma unroll
        for (int fj = 0; fj < 4; ++fj) {
            int col = wc * 64 + fj * 16 + lr;
            bh[fj] = *(const f16x8*)&Bs[0][col][ks];
            bl[fj] = *(const f16x8*)&Bs[1][col][ks];
        }
#pragma unroll
        for (int fi = 0; fi < 4; ++fi)
#pragma unroll
            for (int fj = 0; fj < 4; ++fj) {
                acc[fi][fj] = __builtin_amdgcn_mfma_f32_16x16x32_f16(ah[fi], bh[fj], acc[fi][fj], 0, 0, 0);
                acc[fi][fj] = __builtin_amdgcn_mfma_f32_16x16x32_f16(ah[fi], bl[fj], acc[fi][fj], 0, 0, 0);
                acc[fi][fj] = __builtin_amdgcn_mfma_f32_16x16x32_f16(al[fi], bh[fj], acc[fi][fj], 0, 0, 0);
            }
        __syncthreads();
    }
    // epilogue: C/D layout (m89-verified): col = lane&15, row = (lane>>4)*4 + reg
    int lr = l & 15, lq = l >> 4;
#pragma unroll
    for (int fi = 0; fi < 4; ++fi)
#pragma unroll
        for (int fj = 0; fj < 4; ++fj)
#pragma unroll
            for (int r = 0; r < 4; ++r) {
                int row = row0 + wr * 64 + fi * 16 + lq * 4 + r;
                int col = col0 + wc * 64 + fj * 16 + lr;
                if (row < M) C[(long)row * 512 + col] = acc[fi][fj][r];
            }
}

// ---------------- generic tiled f32 GEMM (small GEMMs + fallback) ----------------
__global__ __launch_bounds__(256) void sgemm64(const float* __restrict__ A,
                                               const float* __restrict__ B,
                                               float* __restrict__ C,
                                               int M, int N, int K) {
    __shared__ float As[16][68];
    __shared__ float Bs[16][68];
    int t = threadIdx.x;
    int tx = t & 15, ty = t >> 4;
    int row0 = blockIdx.y * 64, col0 = blockIdx.x * 64;
    float acc[4][4] = {};
    for (int k0 = 0; k0 < K; k0 += 16) {
#pragma unroll
        for (int i = 0; i < 4; ++i) {
            int idx = t * 4 + i;
            int r = idx >> 4, kk = idx & 15;
            int gr = row0 + r, gk = k0 + kk;
            As[kk][r] = (gr < M && gk < K) ? A[(long)gr * K + gk] : 0.f;
        }
#pragma unroll
        for (int i = 0; i < 4; ++i) {
            int idx = t * 4 + i;
            int kk = idx >> 6, c = idx & 63;
            int gk = k0 + kk, gc = col0 + c;
            Bs[kk][c] = (gk < K && gc < N) ? B[(long)gk * N + gc] : 0.f;
        }
        __syncthreads();
#pragma unroll
        for (int kk = 0; kk < 16; ++kk) {
            float a[4], b[4];
#pragma unroll
            for (int i = 0; i < 4; ++i) a[i] = As[kk][ty * 4 + i];
#pragma unroll
            for (int j = 0; j < 4; ++j) b[j] = Bs[kk][tx * 4 + j];
#pragma unroll
            for (int i = 0; i < 4; ++i)
#pragma unroll
                for (int j = 0; j < 4; ++j) acc[i][j] += a[i] * b[j];
        }
        __syncthreads();
    }
#pragma unroll
    for (int i = 0; i < 4; ++i) {
        int r = row0 + ty * 4 + i;
        if (r >= M) continue;
#pragma unroll
        for (int j = 0; j < 4; ++j) {
            int c = col0 + tx * 4 + j;
            if (c < N) C[(long)r * N + c] = acc[i][j];
        }
    }
}

// ---------------- CSR build ----------------
__global__ void count_deg(const int* __restrict__ dst, int E, int* __restrict__ deg) {
    int i = blockIdx.x * blockDim.x + threadIdx.x;
    if (i < E) atomicAdd(&deg[dst[i]], 1);
}

__global__ __launch_bounds__(256) void exclusive_scan(const int* __restrict__ deg,
                                                      int* __restrict__ row_ptr, int N) {
    __shared__ int part[256];
    __shared__ int base[257];
    int t = threadIdx.x;
    int chunk = (N + 255) / 256;
    int lo = t * chunk, hi = min(lo + chunk, N);
    if (lo > N) lo = N;
    if (hi > N) hi = N;
    int s = 0;
    for (int i = lo; i < hi; ++i) s += deg[i];
    part[t] = s;
    __syncthreads();
    if (t == 0) {
        int r = 0;
        for (int i = 0; i < 256; ++i) { base[i] = r; r += part[i]; }
        base[256] = r;
    }
    __syncthreads();
    int run = base[t];
    for (int i = lo; i < hi; ++i) { row_ptr[i] = run; run += deg[i]; }
    if (t == 0) row_ptr[N] = base[256];
}

__global__ void csr_fill(const int* __restrict__ src, const int* __restrict__ dst, int E,
                         const int* __restrict__ row_ptr, int* __restrict__ cursor,
                         int* __restrict__ col) {
    int i = blockIdx.x * blockDim.x + threadIdx.x;
    if (i < E) {
        int d = dst[i];
        int p = row_ptr[d] + atomicAdd(&cursor[d], 1);
        col[p] = src[i];
    }
}

// ---------------- attention scores ----------------
__global__ __launch_bounds__(256) void att_scores(const float* __restrict__ h,
                                                  const float* __restrict__ asrc,
                                                  const float* __restrict__ adst,
                                                  float* __restrict__ es,
                                                  float* __restrict__ ed, int N) {
    int wid = threadIdx.x >> 6, lane = threadIdx.x & 63;
    int n = blockIdx.x * 4 + wid;
    if (n >= N) return;
    const float* hr = h + (long)n * HD;
    float ps[NHEAD], pd[NHEAD];
#pragma unroll
    for (int hh = 0; hh < NHEAD; ++hh) {
        float s = 0.f, d = 0.f;
#pragma unroll
        for (int j = 0; j < 2; ++j) {
            int c = hh * DDIM + lane + j * 64;
            float v = hr[c];
            s += v * asrc[c];
            d += v * adst[c];
        }
        ps[hh] = s; pd[hh] = d;
    }
#pragma unroll
    for (int off = 32; off > 0; off >>= 1) {
#pragma unroll
        for (int hh = 0; hh < NHEAD; ++hh) {
            ps[hh] += __shfl_xor(ps[hh], off);
            pd[hh] += __shfl_xor(pd[hh], off);
        }
    }
    if (lane == 0) {
#pragma unroll
        for (int hh = 0; hh < NHEAD; ++hh) {
            es[n * NHEAD + hh] = ps[hh];
            ed[n * NHEAD + hh] = pd[hh];
        }
    }
}

// ---------------- GAT aggregation ----------------
__global__ __launch_bounds__(256) void gat_aggregate(const float* __restrict__ h,
                                                     const float* __restrict__ es,
                                                     const float* __restrict__ ed,
                                                     const int* __restrict__ row_ptr,
                                                     const int* __restrict__ col,
                                                     const float* __restrict__ bias,
                                                     float* __restrict__ out,
                                                     int N, int concat) {
    int n = blockIdx.x;
    int t = threadIdx.x;
    int lane = t & 63, wid = t >> 6;
    int s0 = row_ptr[n], s1 = row_ptr[n + 1];

    float edv[NHEAD], vself[NHEAD];
#pragma unroll
    for (int hh = 0; hh < NHEAD; ++hh) {
        edv[hh] = ed[n * NHEAD + hh];
        vself[hh] = leaky(es[n * NHEAD + hh] + edv[hh]);
    }
    __shared__ float sred[4][NHEAD];
    __shared__ float m[NHEAD], den[NHEAD];

    float lm[NHEAD] = {-1e30f, -1e30f, -1e30f, -1e30f};
    for (int k = s0 + t; k < s1; k += 256) {
        int sn = col[k];
#pragma unroll
        for (int hh = 0; hh < NHEAD; ++hh)
            lm[hh] = fmaxf(lm[hh], leaky(es[sn * NHEAD + hh] + edv[hh]));
    }
#pragma unroll
    for (int off = 32; off > 0; off >>= 1)
#pragma unroll
        for (int hh = 0; hh < NHEAD; ++hh) lm[hh] = fmaxf(lm[hh], __shfl_xor(lm[hh], off));
    if (lane == 0)
#pragma unroll
        for (int hh = 0; hh < NHEAD; ++hh) sred[wid][hh] = lm[hh];
    __syncthreads();
    if (t < NHEAD) {
        float mm = vself[t];
#pragma unroll
        for (int w = 0; w < 4; ++w) mm = fmaxf(mm, sred[w][t]);
        m[t] = mm;
    }
    __syncthreads();
    float mh[NHEAD];
#pragma unroll
    for (int hh = 0; hh < NHEAD; ++hh) mh[hh] = m[hh];

    float ls[NHEAD] = {0.f, 0.f, 0.f, 0.f};
    for (int k = s0 + t; k < s1; k += 256) {
        int sn = col[k];
#pragma unroll
        for (int hh = 0; hh < NHEAD; ++hh)
            ls[hh] += expf(leaky(es[sn * NHEAD + hh] + edv[hh]) - mh[hh]);
    }
#pragma unroll
    for (int off = 32; off > 0; off >>= 1)
#pragma unroll
        for (int hh = 0; hh < NHEAD; ++hh) ls[hh] += __shfl_xor(ls[hh], off);
    if (lane == 0)
#pragma unroll
        for (int hh = 0; hh < NHEAD; ++hh) sred[wid][hh] = ls[hh];
    __syncthreads();
    if (t < NHEAD)
        den[t] = sred[0][t] + sred[1][t] + sred[2][t] + sred[3][t] + expf(vself[t] - m[t]);
    __syncthreads();
    float inv[NHEAD];
#pragma unroll
    for (int hh = 0; hh < NHEAD; ++hh) inv[hh] = 1.f / (den[hh] + 1e-16f);

    int d0 = t, d1 = t + 256;
    int h0 = t >> 7, h1 = h0 + 2;
    float acc0, acc1;
    {
        float a0 = expf(vself[h0] - mh[h0]) * inv[h0];
        float a1 = expf(vself[h1] - mh[h1]) * inv[h1];
        acc0 = a0 * h[(long)n * HD + d0];
        acc1 = a1 * h[(long)n * HD + d1];
    }
    __shared__ float alph[64 * NHEAD];
    for (int base = s0; base < s1; base += 64) {
        int cnt = min(64, s1 - base);
        if (t < cnt * NHEAD) {
            int e = t >> 2, hh = t & 3;
            int sn = col[base + e];
            float v = leaky(es[sn * NHEAD + hh] + edv[hh]);
            alph[(e << 2) | hh] = expf(v - mh[hh]) * inv[hh];
        }
        __syncthreads();
        for (int e = 0; e < cnt; ++e) {
            int sn = col[base + e];
            const float* hs = h + (long)sn * HD;
            acc0 += alph[(e << 2) | h0] * hs[d0];
            acc1 += alph[(e << 2) | h1] * hs[d1];
        }
        __syncthreads();
    }

    if (concat) {
        out[(long)n * HD + d0] = acc0 + bias[d0];
        out[(long)n * HD + d1] = acc1 + bias[d1];
    } else {
        __shared__ float accs[HD];
        accs[d0] = acc0;
        accs[d1] = acc1;
        __syncthreads();
        if (t < DDIM)
            out[(long)n * DDIM + t] =
                (accs[t] + accs[t + 128] + accs[t + 256] + accs[t + 384]) * 0.25f + bias[t];
    }
}

// ---------------- BatchNorm ----------------
__global__ __launch_bounds__(256) void bn_stats(const float* __restrict__ x,
                                                float* __restrict__ sums, long total, int C) {
    long gid = (long)blockIdx.x * blockDim.x + threadIdx.x;
    long stride = (long)gridDim.x * blockDim.x;  // multiple of C
    int c = (int)(gid % C);
    float s = 0.f, s2 = 0.f;
    for (long i = gid; i < total; i += stride) {
        float v = x[i];
        s += v; s2 += v * v;
    }
    atomicAdd(&sums[c], s);
    atomicAdd(&sums[C + c], s2);
}

__global__ void bn_finalize(const float* __restrict__ sums, const float* __restrict__ g,
                            const float* __restrict__ be, float* __restrict__ ab,
                            float invN, int C) {
    int c = blockIdx.x * blockDim.x + threadIdx.x;
    if (c < C) {
        float mean = sums[c] * invN;
        float var = sums[C + c] * invN - mean * mean;
        float sc = g[c] * rsqrtf(var + BN_EPS);
        ab[c] = sc;
        ab[C + c] = be[c] - mean * sc;
    }
}

__global__ __launch_bounds__(256) void bn_apply_relu(const float* __restrict__ x,
                                                     const float* __restrict__ ab,
                                                     float* __restrict__ y, long total, int C) {
    long gid = (long)blockIdx.x * blockDim.x + threadIdx.x;
    long stride = (long)gridDim.x * blockDim.x;
    for (long i = gid; i < total; i += stride) {
        int c = (int)(i % C);
        y[i] = fmaxf(0.f, x[i] * ab[c] + ab[C + c]);
    }
}

// ---------------- residue -> SSE pooling ----------------
__global__ void count_res(const int* __restrict__ sid, float* __restrict__ cnt, int Nr) {
    int i = blockIdx.x * blockDim.x + threadIdx.x;
    if (i < Nr) atomicAdd(&cnt[sid[i]], 1.f);
}

__global__ __launch_bounds__(256) void pool_res(const float* __restrict__ x,
                                                const int* __restrict__ sid,
                                                float* __restrict__ pooled, int Nr) {
    long total = (long)Nr * DDIM;
    long stride = (long)gridDim.x * blockDim.x;
    for (long i = (long)blockIdx.x * blockDim.x + threadIdx.x; i < total; i += stride) {
        int n = (int)(i / DDIM), c = (int)(i % DDIM);
        atomicAdd(&pooled[(long)sid[n] * DDIM + c], x[i]);
    }
}

__global__ void build_xsse(const float* __restrict__ pooled, const float* __restrict__ cnt,
                           const int* __restrict__ sstype, float* __restrict__ xsse, int Ns) {
    int i = blockIdx.x * blockDim.x + threadIdx.x;
    if (i >= Ns * SSEIN) return;
    int s = i / SSEIN, j = i % SSEIN;
    float c = cnt[s];
    float v;
    if (j < DDIM) v = pooled[(long)s * DDIM + j] / fmaxf(c, 1.f);
    else if (j < DDIM + 3) v = (sstype[s] == (j - DDIM)) ? 1.f : 0.f;
    else v = c / (float)NRES;
    xsse[i] = v;
}

// ---------------- SSE -> domain pooling ----------------
__global__ void pool_dom(const float* __restrict__ x, float* __restrict__ xdom) {
    int d = blockIdx.x, c = threadIdx.x;
    int spd = NSSE / NDOM;
    int r0 = d * spd;
    int r1 = (d == NDOM - 1) ? NSSE : r0 + spd;
    float acc = 0.f;
    for (int r = r0; r < r1; ++r) acc += x[(long)r * DDIM + c];
    xdom[d * DDIM + c] = acc / (float)(r1 - r0);
}

// ---------------- domain GCN ----------------
__global__ __launch_bounds__(256) void gcn_prep(const int* __restrict__ src,
                                                const int* __restrict__ dst, int E,
                                                float* __restrict__ dis) {
    __shared__ float degL[NDOM];
    int t = threadIdx.x;
    if (t < NDOM) degL[t] = 1.f;
    __syncthreads();
    for (int e = t; e < E; e += blockDim.x) atomicAdd(&degL[dst[e]], 1.f);
    __syncthreads();
    if (t < NDOM) dis[t] = rsqrtf(fmaxf(degL[t], 1e-12f));
}

__global__ void gcn_agg(const float* __restrict__ hdom, const int* __restrict__ src,
                        const int* __restrict__ dst, int E, const float* __restrict__ dis,
                        const float* __restrict__ bd, float* __restrict__ outd) {
    int n = blockIdx.x, c = threadIdx.x;
    float dn = dis[n];
    float acc = dn * dn * hdom[n * OUTD + c];
    for (int e = 0; e < E; ++e)
        if (dst[e] == n) acc += dis[src[e]] * dn * hdom[src[e] * OUTD + c];
    outd[n * OUTD + c] = acc + bd[c];
}

__global__ void bn_small_relu(const float* __restrict__ x, const float* __restrict__ g,
                              const float* __restrict__ be, float* __restrict__ y,
                              int N, int C) {
    int c = threadIdx.x;
    if (c >= C) return;
    float s = 0.f, s2 = 0.f;
#pragma unroll 8
    for (int r = 0; r < N; ++r) {
        float v = x[r * C + c];
        s += v; s2 += v * v;
    }
    float mean = s / N;
    float var = s2 / N - mean * mean;
    float sc = g[c] * rsqrtf(var + BN_EPS);
    float sh = be[c] - mean * sc;
#pragma unroll 8
    for (int r = 0; r < N; ++r) y[r * C + c] = fmaxf(0.f, x[r * C + c] * sc + sh);
}

// ---------------- parallel column sum ----------------
__global__ __launch_bounds__(256) void col_sum_atomic(const float* __restrict__ x,
                                                      float* __restrict__ out,
                                                      long total, int C) {
    long gid = (long)blockIdx.x * blockDim.x + threadIdx.x;
    long stride = (long)gridDim.x * blockDim.x;  // multiple of C
    int c = (int)(gid % C);
    float s = 0.f;
    for (long i = gid; i < total; i += stride) s += x[i];
    atomicAdd(&out[c], s);
}

// ---------------- readout ----------------
__global__ __launch_bounds__(256) void readout(const float* __restrict__ sse_sum,
                                               float invNs,
                                               const float* __restrict__ xdom_bn,
                                               const float* __restrict__ Wproj,
                                               const float* __restrict__ bproj,
                                               const float* __restrict__ Wread,
                                               const float* __restrict__ bread,
                                               float* __restrict__ out) {
    int c = threadIdx.x;
    __shared__ float v[2 * OUTD];
    float s = 0.f;
#pragma unroll 8
    for (int k = 0; k < DDIM; ++k) s += sse_sum[k] * Wproj[k * OUTD + c];
    v[c] = s * invNs + bproj[c];
    float dm = 0.f;
#pragma unroll 8
    for (int r = 0; r < NDOM; ++r) dm += xdom_bn[r * OUTD + c];
    v[OUTD + c] = dm / (float)NDOM;
    __syncthreads();
    float o = bread[c];
#pragma unroll 8
    for (int k = 0; k < 2 * OUTD; ++k) o += v[k] * Wread[k * OUTD + c];
    __shared__ float sq[256];
    sq[c] = o * o;
    __syncthreads();
    for (int off = 128; off > 0; off >>= 1) {
        if (c < off) sq[c] += sq[c + off];
        __syncthreads();
    }
    float scale = 1.f / fmaxf(sqrtf(sq[0]), 1e-12f);
    out[c] = o * scale;
}

// ---------------- launcher ----------------
extern "C" void kernel_launch(void* const* d_in, const int* in_sizes, int n_in,
                              void* d_out, int out_size, void* d_ws, size_t ws_size,
                              hipStream_t stream) {
    const float* x_res = (const float*)d_in[0];
    const int* ei_res = (const int*)d_in[1];
    const int* ei_sse = (const int*)d_in[2];
    const int* ei_dom = (const int*)d_in[3];
    const int* res_sse_id = (const int*)d_in[4];
    const int* sse_ss = (const int*)d_in[5];
    const int E_res = in_sizes[1] / 2;
    const int E_sse = in_sizes[2] / 2;
    const int E_dom = in_sizes[3] / 2;
    const int Nr = in_sizes[4];
    const int Ns = in_sizes[5];
    const float* W1 = (const float*)d_in[7];
    const float* asrc1 = (const float*)d_in[8];
    const float* adst1 = (const float*)d_in[9];
    const float* b1 = (const float*)d_in[10];
    const float* g1 = (const float*)d_in[11];
    const float* be1 = (const float*)d_in[12];
    const float* W2 = (const float*)d_in[13];
    const float* asrc2 = (const float*)d_in[14];
    const float* adst2 = (const float*)d_in[15];
    const float* b2 = (const float*)d_in[16];
    const float* g2 = (const float*)d_in[17];
    const float* be2 = (const float*)d_in[18];
    const float* Ws = (const float*)d_in[19];
    const float* asrcs = (const float*)d_in[20];
    const float* adsts = (const float*)d_in[21];
    const float* bs = (const float*)d_in[22];
    const float* gs = (const float*)d_in[23];
    const float* bes = (const float*)d_in[24];
    const float* Wd = (const float*)d_in[25];
    const float* bd = (const float*)d_in[26];
    const float* gd = (const float*)d_in[27];
    const float* bed = (const float*)d_in[28];
    const float* Wproj = (const float*)d_in[29];
    const float* bproj = (const float*)d_in[30];
    const float* Wread = (const float*)d_in[31];
    const float* bread = (const float*)d_in[32];

    // ---- workspace layout: clamp pointers, track unclamped need for fallback decision ----
    char* w = (char*)d_ws;
    size_t off = 0, need = 0;
    auto alloc = [&](size_t bytes) -> char* {
        char* p = w + off;
        size_t inc = (bytes + 255) & ~(size_t)255;
        need += inc;
        if (off + inc > ws_size) inc = (off < ws_size) ? (ws_size - off) : 0;
        off += inc;
        return p;
    };
    float* A     = (float*)alloc((size_t)Nr * HD * 4);   // h1 / h2
    float* Bb    = (float*)alloc((size_t)Nr * HD * 4);   // gat1 out (pre-BN)
    float* C2    = (float*)alloc((size_t)Nr * DDIM * 4);
    float* es    = (float*)alloc((size_t)Nr * NHEAD * 4);
    float* ed    = (float*)alloc((size_t)Nr * NHEAD * 4);
    int* rp_res  = (int*)alloc((size_t)(Nr + 1) * 4);
    int* col_res = (int*)alloc((size_t)E_res * 4);
    int* rp_sse  = (int*)alloc((size_t)(Ns + 1) * 4);
    int* col_sse = (int*)alloc((size_t)E_sse * 4);
    float* xsse  = (float*)alloc((size_t)Ns * SSEIN * 4);
    float* h_s   = (float*)alloc((size_t)Ns * HD * 4);
    float* xs_o  = (float*)alloc((size_t)Ns * DDIM * 4);
    float* xdom  = (float*)alloc((size_t)NDOM * DDIM * 4);
    float* hdom  = (float*)alloc((size_t)NDOM * OUTD * 4);
    float* gdom  = (float*)alloc((size_t)NDOM * OUTD * 4);
    float* gdom2 = (float*)alloc((size_t)NDOM * OUTD * 4);
    float* dis   = (float*)alloc((size_t)NDOM * 4);
    float* ab1   = (float*)alloc((size_t)2 * HD * 4);
    float* ab2   = (float*)alloc((size_t)2 * DDIM * 4);
    float* ab_s  = (float*)alloc((size_t)2 * DDIM * 4);
    // zeroed region (single memset)
    char* zbase = w + off;
    int* deg_res  = (int*)alloc((size_t)Nr * 4);
    int* cur_res  = (int*)alloc((size_t)Nr * 4);
    int* deg_sse  = (int*)alloc((size_t)Ns * 4);
    int* cur_sse  = (int*)alloc((size_t)Ns * 4);
    float* cnt    = (float*)alloc((size_t)Ns * 4);
    float* pooled = (float*)alloc((size_t)Ns * DDIM * 4);
    float* bsum1  = (float*)alloc((size_t)2 * HD * 4);
    float* bsum2  = (float*)alloc((size_t)2 * DDIM * 4);
    float* bsum_s = (float*)alloc((size_t)2 * DDIM * 4);
    float* sse_g  = (float*)alloc((size_t)DDIM * 4);   // zeroed: col_sum_atomic target
    size_t zbytes = (size_t)((w + off) - zbase);
    // f16 split buffers
    f16* A1hi  = (f16*)alloc((size_t)Nr * KP1 * 2);
    f16* A1lo  = (f16*)alloc((size_t)Nr * KP1 * 2);
    f16* W1thi = (f16*)alloc((size_t)HD * KP1 * 2);
    f16* W1tlo = (f16*)alloc((size_t)HD * KP1 * 2);
    f16* W2thi = (f16*)alloc((size_t)HD * HD * 2);
    f16* W2tlo = (f16*)alloc((size_t)HD * HD * 2);
    // A2 aliases A1's region (disjoint lifetimes)
    f16* A2hi = A1hi;
    f16* A2lo = A1hi + (size_t)Nr * HD;
    bool use_mfma = (need <= ws_size);
    (void)n_in; (void)out_size;

    hipMemsetAsync(zbase, 0, zbytes, stream);

    const int* src_res = ei_res;
    const int* dst_res = ei_res + E_res;
    const int* src_sse = ei_sse;
    const int* dst_sse = ei_sse + E_sse;
    const int* src_dom = ei_dom;
    const int* dst_dom = ei_dom + E_dom;

    // CSR builds
    count_deg<<<(E_res + 255) / 256, 256, 0, stream>>>(dst_res, E_res, deg_res);
    exclusive_scan<<<1, 256, 0, stream>>>(deg_res, rp_res, Nr);
    csr_fill<<<(E_res + 255) / 256, 256, 0, stream>>>(src_res, dst_res, E_res, rp_res, cur_res, col_res);
    count_deg<<<(E_sse + 255) / 256, 256, 0, stream>>>(dst_sse, E_sse, deg_sse);
    exclusive_scan<<<1, 256, 0, stream>>>(deg_sse, rp_sse, Ns);
    csr_fill<<<(E_sse + 255) / 256, 256, 0, stream>>>(src_sse, dst_sse, E_sse, rp_sse, cur_sse, col_sse);

    int RB = (Nr + 127) / 128;                 // row panels
    int gemm_blocks = 32 * ((RB + 7) / 8);     // 4 col-blocks x padded rows (swizzled 1D)

    // ---- Level 1, GAT1 (concat) ----
    if (use_mfma) {
        split_rows<<<2048, 256, 0, stream>>>(x_res, A1hi, A1lo, Nr, FIN, KP1);
        split_w_t<<<512, 256, 0, stream>>>(W1, W1thi, W1tlo, FIN, HD, KP1);
        split_w_t<<<512, 256, 0, stream>>>(W2, W2thi, W2tlo, HD, HD, HD);
        mfma_gemm<<<gemm_blocks, 256, 0, stream>>>(A1hi, A1lo, W1thi, W1tlo, A, Nr, RB, KP1);
    } else {
        sgemm64<<<dim3(HD / 64, (Nr + 63) / 64), 256, 0, stream>>>(x_res, W1, A, Nr, HD, FIN);
    }
    att_scores<<<(Nr + 3) / 4, 256, 0, stream>>>(A, asrc1, adst1, es, ed, Nr);
    gat_aggregate<<<Nr, 256, 0, stream>>>(A, es, ed, rp_res, col_res, b1, Bb, Nr, 1);
    bn_stats<<<512, 256, 0, stream>>>(Bb, bsum1, (long)Nr * HD, HD);
    bn_finalize<<<2, 256, 0, stream>>>(bsum1, g1, be1, ab1, 1.f / Nr, HD);

    // ---- Level 1, GAT2 (mean heads) ----
    if (use_mfma) {
        bn_apply_split<<<2048, 256, 0, stream>>>(Bb, ab1, A2hi, A2lo, (long)Nr * HD, HD);
        mfma_gemm<<<gemm_blocks, 256, 0, stream>>>(A2hi, A2lo, W2thi, W2tlo, A, Nr, RB, HD);
    } else {
        bn_apply_relu<<<2048, 256, 0, stream>>>(Bb, ab1, Bb, (long)Nr * HD, HD);
        sgemm64<<<dim3(HD / 64, (Nr + 63) / 64), 256, 0, stream>>>(Bb, W2, A, Nr, HD, HD);
    }
    att_scores<<<(Nr + 3) / 4, 256, 0, stream>>>(A, asrc2, adst2, es, ed, Nr);
    gat_aggregate<<<Nr, 256, 0, stream>>>(A, es, ed, rp_res, col_res, b2, C2, Nr, 0);
    bn_stats<<<512, 256, 0, stream>>>(C2, bsum2, (long)Nr * DDIM, DDIM);
    bn_finalize<<<1, 128, 0, stream>>>(bsum2, g2, be2, ab2, 1.f / Nr, DDIM);
    bn_apply_relu<<<2048, 256, 0, stream>>>(C2, ab2, C2, (long)Nr * DDIM, DDIM);

    // ---- pool residues -> SSE ----
    count_res<<<(Nr + 255) / 256, 256, 0, stream>>>(res_sse_id, cnt, Nr);
    pool_res<<<2048, 256, 0, stream>>>(C2, res_sse_id, pooled, Nr);
    build_xsse<<<(Ns * SSEIN + 255) / 256, 256, 0, stream>>>(pooled, cnt, sse_ss, xsse, Ns);

    // ---- Level 2: SSE GAT ----
    sgemm64<<<dim3(HD / 64, (Ns + 63) / 64), 256, 0, stream>>>(xsse, Ws, h_s, Ns, HD, SSEIN);
    att_scores<<<(Ns + 3) / 4, 256, 0, stream>>>(h_s, asrcs, adsts, es, ed, Ns);
    gat_aggregate<<<Ns, 256, 0, stream>>>(h_s, es, ed, rp_sse, col_sse, bs, xs_o, Ns, 0);
    bn_stats<<<512, 256, 0, stream>>>(xs_o, bsum_s, (long)Ns * DDIM, DDIM);
    bn_finalize<<<1, 128, 0, stream>>>(bsum_s, gs, bes, ab_s, 1.f / Ns, DDIM);
    bn_apply_relu<<<512, 256, 0, stream>>>(xs_o, ab_s, xs_o, (long)Ns * DDIM, DDIM);

    // ---- pool SSE -> domains; GCN; BN ----
    pool_dom<<<NDOM, DDIM, 0, stream>>>(xs_o, xdom);
    sgemm64<<<dim3(OUTD / 64, 1), 256, 0, stream>>>(xdom, Wd, hdom, NDOM, OUTD, DDIM);
    gcn_prep<<<1, 256, 0, stream>>>(src_dom, dst_dom, E_dom, dis);
    gcn_agg<<<NDOM, OUTD, 0, stream>>>(hdom, src_dom, dst_dom, E_dom, dis, bd, gdom);
    bn_small_relu<<<1, OUTD, 0, stream>>>(gdom, gd, bed, gdom2, NDOM, OUTD);

    // ---- readout ----
    col_sum_atomic<<<128, 256, 0, stream>>>(xs_o, sse_g, (long)Ns * DDIM, DDIM);
    readout<<<1, OUTD, 0, stream>>>(sse_g, 1.f / (float)Ns, gdom2, Wproj, bproj, Wread, bread, (float*)d_out);
}